// Round 3
// baseline (826.528 us; speedup 1.0000x reference)
//
#include <hip/hip_runtime.h>
#include <math.h>

// Problem constants
#define B_     8
#define S_     4
#define H_     50
#define NH_    200
#define EHH_   400
#define L_     2
#define HID_   128
#define FDIM_  79          // 44 + 20 + 15
#define EDIM_  161         // 2*FDIM + 3
#define NN_    250         // H + NH
#define BS_    32          // B*S
#define NROW_  1600        // BS*H (one block per output row in edge kernel)
#define FS_    80          // feat row stride
#define MSTR_  136         // s_m stride in bf16 (128 + 8)
#define NDIM_  207         // FDIM + HID
#define HVB_   1600        // hjW1 heavy-region base row

// Workspace layout (float offsets)
#define OFF_FEATH  0         // BS*H*80 = 128000
#define OFF_X      128000    // BS*NN*4 = 32000
#define OFF_X0H    160000    // 6400
#define OFF_HHCOL  166400    // 3200 (int)  sorted hh cols, 400 per b
#define OFF_HHEM   169600    // 3200        sorted hh edge masks
#define OFF_HHOFF  172800    // 512 (int)   CSR row offsets, 64 per b (0..50 used)
#define OFF_AGG0   173312    // aggx(6400) + aggm(204800) = 211200
#define AGGSTRIDE_ 211200
#define OFF_AGG1   384512
#define OFF_HIW1   595712    // fp32 1600*128 (b1 + t*w160 folded in)
#define OFF_HJW1   800512    // fp32 4800*128: [0,1600) h cur | [1600,3200) hv l0 | [3200,4800) hv l1
#define OFF_WP     1414912   // 65536 ushort

typedef __attribute__((ext_vector_type(8))) short short8;
typedef __attribute__((ext_vector_type(4))) float f32x4;

__device__ __forceinline__ float silu_(float v) {
    return v * __builtin_amdgcn_rcpf(1.0f + __expf(-v));
}
__device__ __forceinline__ unsigned short f2bf(float f) {
    unsigned int u = __float_as_uint(f);
    unsigned int r = (u + 0x7fffu + ((u >> 16) & 1u)) >> 16;
    return (unsigned short)r;
}

// ================= fused setup =================
#define HV_BLKS_    1600   // heavy hjW1 both layers: 409600
#define PACK_BLKS_  256    // 65536
#define SORT_BLKS_  8      // counting-sort hh edges by row, per b; emits CSR
#define HROW_BLKS_  200    // 400*128
#define FEAT_BLKS_  125    // 400*80
#define XI_BLKS_    32     // 8000
#define SETUP_BLKS_ (HV_BLKS_ + PACK_BLKS_ + SORT_BLKS_ + HROW_BLKS_ + FEAT_BLKS_ + XI_BLKS_)

__global__ __launch_bounds__(256) void k_setup(
    const float* __restrict__ x_h, const float* __restrict__ x_hv,
    const int* __restrict__ bound,
    const int* __restrict__ ehh, const float* __restrict__ em_hh,
    const float* __restrict__ W1, const float* __restrict__ b1,
    const float* __restrict__ t_in,
    const float* __restrict__ W2, const float* __restrict__ Wc1,
    const int* __restrict__ lab_h, const int* __restrict__ pos_h,
    const int* __restrict__ lab_hv, const int* __restrict__ pos_hv,
    const int* __restrict__ pep,
    float* __restrict__ feat_h,
    float* __restrict__ x, float* __restrict__ x0h,
    int* __restrict__ hhcol, float* __restrict__ hhem, int* __restrict__ hhoff,
    float* __restrict__ hiW1, float* __restrict__ hjW1,
    unsigned short* __restrict__ Wp)
{
    int blk = blockIdx.x, t = threadIdx.x;
    if (blk < HV_BLKS_) {
        int g = blk*256 + t;                 // [0, 409600)
        int l = g / 204800;
        int r = g - l*204800;
        int node = r >> 7, col = r & 127;    // node = b*NH + nh
        int b = node / NH_;
        int label = lab_hv[node], pos = pos_hv[node];
        int aa = pep[b*15 + pos - 1];
        const float* W1l = W1 + l*EDIM_*HID_;
        float hj = W1l[(FDIM_ + label)*HID_ + col]
                 + W1l[(FDIM_ + 44 + aa)*HID_ + col]
                 + W1l[(FDIM_ + 64 + pos - 1)*HID_ + col];
        hjW1[(size_t)(HVB_ + l*1600 + node)*HID_ + col] = hj;
        return;
    }
    blk -= HV_BLKS_;
    if (blk < PACK_BLKS_) {
        int g = blk*256 + t;
        int idx = g & 16383;
        int lm  = g >> 14;
        int l = lm >> 1, mat = lm & 1;
        int j = idx & 7, q = (idx >> 3) & 3, n = (idx >> 5) & 127, kc = idx >> 12;
        int k = kc*32 + q*8 + j;
        const float* W = (mat == 0 ? W2 : Wc1) + l*HID_*HID_;
        Wp[g] = f2bf(W[k*HID_ + n]);
        return;
    }
    blk -= PACK_BLKS_;
    if (blk < SORT_BLKS_) {
        // counting-sort the 400 hh edges of batch b by row; emit CSR offsets
        int b = blk;
        __shared__ int scnt[64];
        __shared__ int srow[EHH_], scol[EHH_];
        __shared__ float sem[EHH_];
        if (t < 64) scnt[t] = 0;
        __syncthreads();
        for (int e = t; e < EHH_; e += 256) {
            int r = ehh[(b*EHH_ + e)*2 + 0];
            srow[e] = r;
            scol[e] = ehh[(b*EHH_ + e)*2 + 1];
            sem[e]  = em_hh[b*EHH_ + e];
            atomicAdd(&scnt[r], 1);
        }
        __syncthreads();
        if (t == 0) {
            int acc = 0;
            for (int i = 0; i < H_; ++i) { int v = scnt[i]; scnt[i] = acc; acc += v; }
        }
        __syncthreads();
        if (t < 51) hhoff[b*64 + t] = (t < H_) ? scnt[t] : EHH_;
        __syncthreads();
        for (int e = t; e < EHH_; e += 256) {
            int r = srow[e];
            int pos = atomicAdd(&scnt[r], 1);
            hhcol[b*EHH_ + pos] = scol[e];
            hhem [b*EHH_ + pos] = sem[e];
        }
        return;
    }
    blk -= SORT_BLKS_;
    if (blk < HROW_BLKS_) {
        // h-node layer-0 projections; fold b1 and t*w160 into hiW1
        int g = blk*256 + t;                 // [0, 51200)
        int node = g >> 7, col = g & 127;    // node = b*H + h
        int b = node / H_;
        int label = lab_h[node], pos = pos_h[node];
        int aa = pep[b*15 + pos - 1];
        const float* W1l = W1;               // layer 0
        float hi = W1l[label*HID_ + col]
                 + W1l[(44 + aa)*HID_ + col]
                 + W1l[(64 + pos - 1)*HID_ + col]
                 + b1[col]
                 + t_in[b] * W1l[160*HID_ + col];
        float hj = W1l[(FDIM_ + label)*HID_ + col]
                 + W1l[(FDIM_ + 44 + aa)*HID_ + col]
                 + W1l[(FDIM_ + 64 + pos - 1)*HID_ + col];
        int h = node % H_;
        #pragma unroll
        for (int s = 0; s < S_; ++s) {
            int row = (b*S_ + s)*H_ + h;
            hiW1[(size_t)row*HID_ + col] = hi;
            hjW1[(size_t)row*HID_ + col] = hj;
        }
        return;
    }
    blk -= HROW_BLKS_;
    if (blk < FEAT_BLKS_) {
        int g = blk*256 + t;                 // [0, 32000)
        int node = g / FS_, f = g % FS_;     // node = b*H + h
        int b = node / H_, h = node % H_;
        int label = lab_h[node], pos = pos_h[node];
        int aa = pep[b*15 + pos - 1];
        float v = 0.f;
        if (f < 44)      v = (f == label)          ? 1.0f : 0.0f;
        else if (f < 64) v = ((f - 44) == aa)      ? 1.0f : 0.0f;
        else if (f < 79) v = ((f - 64) == pos - 1) ? 1.0f : 0.0f;
        #pragma unroll
        for (int s = 0; s < S_; ++s)
            feat_h[((b*S_ + s)*H_ + h)*FS_ + f] = v;
        return;
    }
    blk -= FEAT_BLKS_;
    {
        int g = blk*256 + t;
        if (g >= BS_*NN_) return;
        int bs = g / NN_, n = g % NN_;
        int b = bs / S_;
        if (n < H_) {
            int ba = bound[b*H_ + n];
            for (int d = 0; d < 3; ++d) {
                float v = x_h[(bs*H_ + n)*3 + d] + x_hv[(b*NH_ + ba)*3 + d];
                x[g*4 + d] = v;
                x0h[(bs*H_ + n)*4 + d] = v;
            }
        } else {
            int nh = n - H_;
            for (int d = 0; d < 3; ++d) x[g*4 + d] = x_hv[(b*NH_ + nh)*3 + d];
        }
    }
}

// ============ per-layer: one block per output row; MFMA edge MLP, register aggregation ============
// Each wave independently processes 16-edge tiles (ti = w, w+4, ...) of this row's
// edge list (cnt_hh sorted hh edges + 200 grid edges). All per-tile LDS is
// wave-private (wave_barrier ordering). aggm/aggx accumulate in registers;
// single cross-wave combine + direct store.
// __launch_bounds__(256,3): cap VGPR ~168 -> 3 waves/SIMD. Round-2 post-mortem:
// unbounded build used 248 VGPR -> 10% occupancy -> latency-bound regression.
// Per-row biases (b2/bc1/Wc2) live in LDS (s_c rows 3..5), not registers.
__global__ __launch_bounds__(256, 3) void k_edge_mlp(
    const float* __restrict__ x, const float* __restrict__ hiW1,
    const float* __restrict__ hjW1,
    const int* __restrict__ hhcol, const float* __restrict__ hhem,
    const int* __restrict__ hhoff,
    const float* __restrict__ em_hv, const float* __restrict__ bond_in,
    const float* __restrict__ W1,
    const float* __restrict__ b2, const float* __restrict__ bc1,
    const float* __restrict__ Wc2,
    const unsigned short* __restrict__ Wp, int l,
    float* __restrict__ aggx, float* __restrict__ aggm)
{
    __shared__ unsigned short s_m[4][16][MSTR_];   // 17408 B, wave-private 16-row chunks
    __shared__ float s_es[4][16][6];               // diff0..2, dist, bond, emk
    __shared__ int   s_jj[4][16];
    __shared__ float s_c[6][HID_];                 // hi, W1r158, W1r159, b2, bc1, Wc2
    __shared__ float s_mr[4][HID_];
    __shared__ float s_xr[4][4];

    const int t = threadIdx.x, lane = t & 63, w = t >> 6;
    const int l15 = lane & 15, q = lane >> 4;
    const int node = blockIdx.x;                   // bs*H + h
    const int bs = node / H_, h = node - bs*H_;
    const int b = bs / S_;

    const float* W1l = W1 + l*EDIM_*HID_;
    if (t < HID_) {
        s_c[0][t] = hiW1[(size_t)node*HID_ + t];
        s_c[1][t] = W1l[158*HID_ + t];
        s_c[2][t] = W1l[159*HID_ + t];
        s_c[3][t] = b2 [l*HID_ + t];
        s_c[4][t] = bc1[l*HID_ + t];
        s_c[5][t] = Wc2[l*HID_ + t];
    }

    const int hh0 = hhoff[b*64 + h];
    const int cnt = hhoff[b*64 + h + 1] - hh0;
    const int E   = cnt + NH_;                     // total real edges for this row
    const int NT  = (E + 15) >> 4;                 // 16-edge tiles

    const float xi0 = x[(bs*NN_ + h)*4 + 0];
    const float xi1 = x[(bs*NN_ + h)*4 + 1];
    const float xi2 = x[(bs*NN_ + h)*4 + 2];

    float macc[8] = {0.f,0.f,0.f,0.f,0.f,0.f,0.f,0.f};
    float xacc = 0.f;
    const unsigned short* Wp2 = Wp + (size_t)(l*2 + 0)*16384;
    const unsigned short* Wp3 = Wp + (size_t)(l*2 + 1)*16384;
    __syncthreads();                               // s_c ready

    for (int ti = w; ti < NT; ti += 4) {
        // ---- per-edge scalars for this wave's 16 edges ----
        if (lane < 16) {
            int e = ti*16 + lane;
            float d0=0.f,d1=0.f,d2=0.f,dist=0.f,bnd=0.f,em=0.f;
            int jj = bs*H_;                        // padding: valid row, em=0, diff=0
            if (e < E) {
                int col;
                if (e < cnt) {                     // sorted hh edge
                    col = hhcol[b*EHH_ + hh0 + e];
                    em  = hhem [b*EHH_ + hh0 + e];
                    jj  = bs*H_ + col;
                } else {                           // grid edge (row h -> heavy cc)
                    int cc = e - cnt;
                    col = H_ + cc;
                    em  = em_hv [(b*H_ + h)*NH_ + cc];
                    bnd = bond_in[(b*H_ + h)*NH_ + cc];
                    jj  = HVB_ + l*1600 + b*NH_ + cc;
                }
                d0 = xi0 - x[(bs*NN_ + col)*4 + 0];
                d1 = xi1 - x[(bs*NN_ + col)*4 + 1];
                d2 = xi2 - x[(bs*NN_ + col)*4 + 2];
                dist = sqrtf(d0*d0 + d1*d1 + d2*d2);
            }
            s_es[w][lane][0] = d0; s_es[w][lane][1] = d1; s_es[w][lane][2] = d2;
            s_es[w][lane][3] = dist; s_es[w][lane][4] = bnd; s_es[w][lane][5] = em;
            s_jj[w][lane] = jj;
        }
        __builtin_amdgcn_wave_barrier();

        // ---- stage 1: m1 = silu(hi + hj + dist*w158 + bond*w159) ----
        const float dist = s_es[w][l15][3];
        const float bnd  = s_es[w][l15][4];
        const int   jj   = s_jj[w][l15];
        const float* pj  = hjW1 + (size_t)jj*HID_ + q*8;
        short8 afrag[4];
        #pragma unroll
        for (int kc = 0; kc < 4; ++kc) {
            int k0 = kc*32 + q*8;
            float4 c0 = *(const float4*)(pj + kc*32);
            float4 c1 = *(const float4*)(pj + kc*32 + 4);
            float4 h0 = *(const float4*)&s_c[0][k0];
            float4 h1 = *(const float4*)&s_c[0][k0 + 4];
            float4 wa0= *(const float4*)&s_c[1][k0];
            float4 wa1= *(const float4*)&s_c[1][k0 + 4];
            float4 wb0= *(const float4*)&s_c[2][k0];
            float4 wb1= *(const float4*)&s_c[2][k0 + 4];
            short8 fr;
            fr[0] = (short)f2bf(silu_(h0.x + c0.x + dist*wa0.x + bnd*wb0.x));
            fr[1] = (short)f2bf(silu_(h0.y + c0.y + dist*wa0.y + bnd*wb0.y));
            fr[2] = (short)f2bf(silu_(h0.z + c0.z + dist*wa0.z + bnd*wb0.z));
            fr[3] = (short)f2bf(silu_(h0.w + c0.w + dist*wa0.w + bnd*wb0.w));
            fr[4] = (short)f2bf(silu_(h1.x + c1.x + dist*wa1.x + bnd*wb1.x));
            fr[5] = (short)f2bf(silu_(h1.y + c1.y + dist*wa1.y + bnd*wb1.y));
            fr[6] = (short)f2bf(silu_(h1.z + c1.z + dist*wa1.z + bnd*wb1.z));
            fr[7] = (short)f2bf(silu_(h1.w + c1.w + dist*wa1.w + bnd*wb1.w));
            afrag[kc] = fr;
        }

        // ---- stage 2: m = silu(m1 @ W2 + b2) * emask; accumulate column sums ----
        float em4[4];
        #pragma unroll
        for (int r = 0; r < 4; ++r) em4[r] = s_es[w][q*4 + r][5];
        #pragma unroll
        for (int nt = 0; nt < 8; ++nt) {
            float bias = s_c[3][nt*16 + l15];
            f32x4 c = {bias, bias, bias, bias};
            #pragma unroll
            for (int kc = 0; kc < 4; ++kc) {
                short8 bf = *(const short8*)&Wp2[(size_t)((kc*128 + nt*16 + l15)*4 + q)*8];
                c = __builtin_amdgcn_mfma_f32_16x16x32_bf16(afrag[kc], bf, c, 0, 0, 0);
            }
            #pragma unroll
            for (int r = 0; r < 4; ++r) {
                float mv = silu_(c[r]) * em4[r];   // padding edges have em=0 -> mv=0
                s_m[w][q*4 + r][nt*16 + l15] = f2bf(mv);
                macc[nt] += mv;
            }
        }
        __builtin_amdgcn_wave_barrier();

        // ---- stage 3: cw = silu(m @ Wc1 + bc1) @ Wc2; accumulate diff*cw ----
        short8 af2[4];
        #pragma unroll
        for (int kc = 0; kc < 4; ++kc)
            af2[kc] = *(const short8*)&s_m[w][l15][kc*32 + q*8];
        float p[4] = {0.f, 0.f, 0.f, 0.f};
        #pragma unroll
        for (int nt = 0; nt < 8; ++nt) {
            float bias = s_c[4][nt*16 + l15];
            f32x4 c = {bias, bias, bias, bias};
            #pragma unroll
            for (int kc = 0; kc < 4; ++kc) {
                short8 bf = *(const short8*)&Wp3[(size_t)((kc*128 + nt*16 + l15)*4 + q)*8];
                c = __builtin_amdgcn_mfma_f32_16x16x32_bf16(af2[kc], bf, c, 0, 0, 0);
            }
            float wcv = s_c[5][nt*16 + l15];
            #pragma unroll
            for (int r = 0; r < 4; ++r)
                p[r] += silu_(c[r]) * wcv;
        }
        // reduce p over the 16 l15-lanes of this q-group -> cw per edge q*4+r
        #pragma unroll
        for (int m = 1; m < 16; m <<= 1) {
            #pragma unroll
            for (int r = 0; r < 4; ++r) p[r] += __shfl_xor(p[r], m, 64);
        }
        if (l15 < 3) {                              // lane d=l15 accumulates dim d
            #pragma unroll
            for (int r = 0; r < 4; ++r)
                xacc += s_es[w][q*4 + r][l15] * p[r];   // padding: diff=0
        }
        __builtin_amdgcn_wave_barrier();
    }

    // ---- cross-q, cross-wave combine; direct stores (no atomics, no pre-zero) ----
    #pragma unroll
    for (int nt = 0; nt < 8; ++nt) {
        macc[nt] += __shfl_xor(macc[nt], 16, 64);
        macc[nt] += __shfl_xor(macc[nt], 32, 64);
    }
    if (q == 0) {
        #pragma unroll
        for (int nt = 0; nt < 8; ++nt) s_mr[w][nt*16 + l15] = macc[nt];
    }
    xacc += __shfl_xor(xacc, 16, 64);
    xacc += __shfl_xor(xacc, 32, 64);
    if (q == 0 && l15 < 3) s_xr[w][l15] = xacc;
    __syncthreads();
    if (t < HID_) {
        aggm[(size_t)node*HID_ + t] = s_mr[0][t] + s_mr[1][t] + s_mr[2][t] + s_mr[3][t];
    } else if (t < HID_ + 3) {
        int d = t - HID_;
        aggx[node*4 + d] = s_xr[0][d] + s_xr[1][d] + s_xr[2][d] + s_xr[3][d];
    }
}

// ====== per-layer: node update (8 nodes/block) + next-layer W1 (folded) + out ======
__global__ __launch_bounds__(128) void k_update(
    float* __restrict__ feat_h, float* __restrict__ x,
    const float* __restrict__ aggm, const float* __restrict__ aggx,
    const float* __restrict__ Wn1, const float* __restrict__ bn1,
    const float* __restrict__ Wn2, const float* __restrict__ bn2, int l,
    const float* __restrict__ W1, const float* __restrict__ b1,
    const float* __restrict__ t_in,
    float* __restrict__ hiW1, float* __restrict__ hjW1, int do_w1,
    const float* __restrict__ x0h, const float* __restrict__ amask,
    float* __restrict__ out)
{
    __shared__ float s_in[8][NDIM_ + 1];
    __shared__ float s_u[8][HID_ + 1];
    int node0 = blockIdx.x * 8;            // bs*H + h
    int t = threadIdx.x;
    for (int idx = t; idx < 8*(NDIM_ + 1); idx += 128) {
        int g = idx / (NDIM_ + 1), k = idx % (NDIM_ + 1);
        float v = 0.f;
        if (k < FDIM_)      v = feat_h[(node0 + g)*FS_ + k];
        else if (k < NDIM_) v = aggm[(size_t)(node0 + g)*HID_ + (k - FDIM_)];
        s_in[g][k] = v;
    }
    __syncthreads();
    const float* Wn1l = Wn1 + l*NDIM_*HID_;
    float acc[8];
    float bv = bn1[l*HID_ + t];
    #pragma unroll
    for (int g = 0; g < 8; ++g) acc[g] = bv;
    for (int k = 0; k < NDIM_; ++k) {
        float wv = Wn1l[k*HID_ + t];
        #pragma unroll
        for (int g = 0; g < 8; ++g) acc[g] += s_in[g][k] * wv;
    }
    #pragma unroll
    for (int g = 0; g < 8; ++g) s_u[g][t] = silu_(acc[g]);
    __syncthreads();
    if (t < FDIM_) {
        const float* Wn2l = Wn2 + l*HID_*FDIM_;
        float acc2[8];
        float b2v = bn2[l*FDIM_ + t];
        #pragma unroll
        for (int g = 0; g < 8; ++g) acc2[g] = b2v;
        for (int k = 0; k < HID_; ++k) {
            float wv = Wn2l[k*FDIM_ + t];
            #pragma unroll
            for (int g = 0; g < 8; ++g) acc2[g] += s_u[g][k] * wv;
        }
        #pragma unroll
        for (int g = 0; g < 8; ++g) {
            float nf = s_in[g][t] + acc2[g];
            feat_h[(node0 + g)*FS_ + t] = nf;
            s_in[g][t] = nf;
        }
    } else if (t >= 96 && t < 120) {
        int idx = t - 96, g = idx / 3, d = idx % 3;
        int node = node0 + g;
        int bs = node / H_, h = node % H_;
        float xv = x[(bs*NN_ + h)*4 + d] + aggx[node*4 + d];
        x[(bs*NN_ + h)*4 + d] = xv;
        if (!do_w1) {
            int b = bs / S_;
            out[node*3 + d] = (xv - x0h[node*4 + d]) * amask[b*H_ + h];
        }
    }
    if (!do_w1) return;
    __syncthreads();
    // ---- next-layer W1 projections (fold b1 + t*w160 into hiW1) ----
    {
        const float* W1n = W1 + (l + 1)*EDIM_*HID_;
        float w160 = W1n[160*HID_ + t];
        float b1v  = b1[(l + 1)*HID_ + t];
        float hia[8], hja[8];
        #pragma unroll
        for (int g = 0; g < 8; ++g) { hia[g] = 0.f; hja[g] = 0.f; }
        for (int f = 0; f < FDIM_; ++f) {
            float wi = W1n[f*HID_ + t];
            float wj = W1n[(FDIM_ + f)*HID_ + t];
            #pragma unroll
            for (int g = 0; g < 8; ++g) {
                float v = s_in[g][f];
                hia[g] += v * wi;
                hja[g] += v * wj;
            }
        }
        #pragma unroll
        for (int g = 0; g < 8; ++g) {
            int node = node0 + g;
            int b = (node / H_) / S_;
            hiW1[(size_t)node*HID_ + t] = hia[g] + b1v + t_in[b]*w160;
            hjW1[(size_t)node*HID_ + t] = hja[g];
        }
    }
}

// ---------------- launch ----------------
extern "C" void kernel_launch(void* const* d_in, const int* in_sizes, int n_in,
                              void* d_out, int out_size, void* d_ws, size_t ws_size,
                              hipStream_t stream)
{
    const float* t_in  = (const float*)d_in[0];
    const float* x_h   = (const float*)d_in[1];
    const float* x_hv  = (const float*)d_in[2];
    const float* bond  = (const float*)d_in[3];
    const float* em_hv = (const float*)d_in[4];
    const float* em_hh = (const float*)d_in[5];
    const float* amask = (const float*)d_in[6];
    const float* W1    = (const float*)d_in[7];
    const float* b1    = (const float*)d_in[8];
    const float* W2    = (const float*)d_in[9];
    const float* b2    = (const float*)d_in[10];
    const float* Wc1   = (const float*)d_in[11];
    const float* bc1   = (const float*)d_in[12];
    const float* Wc2   = (const float*)d_in[13];
    const float* Wn1   = (const float*)d_in[14];
    const float* bn1   = (const float*)d_in[15];
    const float* Wn2   = (const float*)d_in[16];
    const float* bn2   = (const float*)d_in[17];
    const int* pep     = (const int*)d_in[18];
    const int* lab_hv  = (const int*)d_in[19];
    const int* lab_h   = (const int*)d_in[20];
    const int* pos_hv  = (const int*)d_in[21];
    const int* pos_h   = (const int*)d_in[22];
    const int* ehh     = (const int*)d_in[23];
    const int* bound   = (const int*)d_in[24];

    float* ws     = (float*)d_ws;
    float* feat_h = ws + OFF_FEATH;
    float* x      = ws + OFF_X;
    float* x0h    = ws + OFF_X0H;
    int*   hhcol  = (int*)(ws + OFF_HHCOL);
    float* hhem   = ws + OFF_HHEM;
    int*   hhoff  = (int*)(ws + OFF_HHOFF);
    float* hiW1   = ws + OFF_HIW1;
    float* hjW1   = ws + OFF_HJW1;
    unsigned short* Wp = (unsigned short*)(ws + OFF_WP);

    hipLaunchKernelGGL(k_setup, dim3(SETUP_BLKS_), dim3(256), 0, stream,
                       x_h, x_hv, bound, ehh, em_hh,
                       W1, b1, t_in, W2, Wc1,
                       lab_h, pos_h, lab_hv, pos_hv, pep,
                       feat_h, x, x0h, hhcol, hhem, hhoff,
                       hiW1, hjW1, Wp);

    for (int l = 0; l < L_; ++l) {
        float* aggx_l = ws + OFF_AGG0 + (size_t)l*AGGSTRIDE_;
        float* aggm_l = aggx_l + 6400;
        hipLaunchKernelGGL(k_edge_mlp, dim3(NROW_), dim3(256), 0, stream,
                           x, hiW1, hjW1, hhcol, hhem, hhoff, em_hv, bond,
                           W1, b2, bc1, Wc2, Wp, l, aggx_l, aggm_l);
        int do_w1 = (l == 0);
        hipLaunchKernelGGL(k_update, dim3(200), dim3(128), 0, stream,
                           feat_h, x, aggm_l, aggx_l, Wn1, bn1, Wn2, bn2, l,
                           W1, b1, t_in, hiW1, hjW1, do_w1,
                           x0h, amask, (float*)d_out);
    }
}

// Round 4
// 645.750 us; speedup vs baseline: 1.2800x; 1.2800x over previous
//
#include <hip/hip_runtime.h>
#include <math.h>

// Problem constants
#define B_     8
#define S_     4
#define H_     50
#define NH_    200
#define EHH_   400
#define L_     2
#define HID_   128
#define FDIM_  79          // 44 + 20 + 15
#define EDIM_  161         // 2*FDIM + 3
#define NN_    250         // H + NH
#define BS_    32          // B*S
#define NROW_  1600        // BS*H (one block per output row in edge kernel)
#define FS_    80          // feat row stride
#define MSTR_  136         // s_m stride in bf16 (128 + 8)
#define NDIM_  207         // FDIM + HID
#define HVB_   1600        // hjW1 heavy-region base row

// Workspace layout (float offsets)
#define OFF_FEATH  0         // BS*H*80 = 128000
#define OFF_X      128000    // BS*NN*4 = 32000
#define OFF_X0H    160000    // 6400
#define OFF_HHCOL  166400    // 3200 (int)  sorted hh cols, 400 per b
#define OFF_HHEM   169600    // 3200        sorted hh edge masks
#define OFF_HHOFF  172800    // 512 (int)   CSR row offsets, 64 per b (0..50 used)
#define OFF_AGG0   173312    // aggx(6400) + aggm(204800) = 211200
#define AGGSTRIDE_ 211200
#define OFF_AGG1   384512
#define OFF_HIW1   595712    // fp32 1600*128 (b1 + t*w160 folded in)
#define OFF_HJW1   800512    // fp32 4800*128: [0,1600) h cur | [1600,3200) hv l0 | [3200,4800) hv l1
#define OFF_WP     1414912   // 65536 ushort

typedef __attribute__((ext_vector_type(8))) short short8;
typedef __attribute__((ext_vector_type(4))) float f32x4;

__device__ __forceinline__ float silu_(float v) {
    return v * __builtin_amdgcn_rcpf(1.0f + __expf(-v));
}
__device__ __forceinline__ unsigned short f2bf(float f) {
    unsigned int u = __float_as_uint(f);
    unsigned int r = (u + 0x7fffu + ((u >> 16) & 1u)) >> 16;
    return (unsigned short)r;
}

// ================= fused setup =================
#define HV_BLKS_    1600   // heavy hjW1 both layers: 409600
#define PACK_BLKS_  256    // 65536
#define SORT_BLKS_  8      // counting-sort hh edges by row, per b; emits CSR
#define HROW_BLKS_  200    // 400*128
#define FEAT_BLKS_  125    // 400*80
#define XI_BLKS_    32     // 8000
#define SETUP_BLKS_ (HV_BLKS_ + PACK_BLKS_ + SORT_BLKS_ + HROW_BLKS_ + FEAT_BLKS_ + XI_BLKS_)

__global__ __launch_bounds__(256) void k_setup(
    const float* __restrict__ x_h, const float* __restrict__ x_hv,
    const int* __restrict__ bound,
    const int* __restrict__ ehh, const float* __restrict__ em_hh,
    const float* __restrict__ W1, const float* __restrict__ b1,
    const float* __restrict__ t_in,
    const float* __restrict__ W2, const float* __restrict__ Wc1,
    const int* __restrict__ lab_h, const int* __restrict__ pos_h,
    const int* __restrict__ lab_hv, const int* __restrict__ pos_hv,
    const int* __restrict__ pep,
    float* __restrict__ feat_h,
    float* __restrict__ x, float* __restrict__ x0h,
    int* __restrict__ hhcol, float* __restrict__ hhem, int* __restrict__ hhoff,
    float* __restrict__ hiW1, float* __restrict__ hjW1,
    unsigned short* __restrict__ Wp)
{
    int blk = blockIdx.x, t = threadIdx.x;
    if (blk < HV_BLKS_) {
        int g = blk*256 + t;                 // [0, 409600)
        int l = g / 204800;
        int r = g - l*204800;
        int node = r >> 7, col = r & 127;    // node = b*NH + nh
        int b = node / NH_;
        int label = lab_hv[node], pos = pos_hv[node];
        int aa = pep[b*15 + pos - 1];
        const float* W1l = W1 + l*EDIM_*HID_;
        float hj = W1l[(FDIM_ + label)*HID_ + col]
                 + W1l[(FDIM_ + 44 + aa)*HID_ + col]
                 + W1l[(FDIM_ + 64 + pos - 1)*HID_ + col];
        hjW1[(size_t)(HVB_ + l*1600 + node)*HID_ + col] = hj;
        return;
    }
    blk -= HV_BLKS_;
    if (blk < PACK_BLKS_) {
        int g = blk*256 + t;
        int idx = g & 16383;
        int lm  = g >> 14;
        int l = lm >> 1, mat = lm & 1;
        int j = idx & 7, q = (idx >> 3) & 3, n = (idx >> 5) & 127, kc = idx >> 12;
        int k = kc*32 + q*8 + j;
        const float* W = (mat == 0 ? W2 : Wc1) + l*HID_*HID_;
        Wp[g] = f2bf(W[k*HID_ + n]);
        return;
    }
    blk -= PACK_BLKS_;
    if (blk < SORT_BLKS_) {
        // counting-sort the 400 hh edges of batch b by row; emit CSR offsets
        int b = blk;
        __shared__ int scnt[64];
        __shared__ int srow[EHH_], scol[EHH_];
        __shared__ float sem[EHH_];
        if (t < 64) scnt[t] = 0;
        __syncthreads();
        for (int e = t; e < EHH_; e += 256) {
            int r = ehh[(b*EHH_ + e)*2 + 0];
            srow[e] = r;
            scol[e] = ehh[(b*EHH_ + e)*2 + 1];
            sem[e]  = em_hh[b*EHH_ + e];
            atomicAdd(&scnt[r], 1);
        }
        __syncthreads();
        if (t == 0) {
            int acc = 0;
            for (int i = 0; i < H_; ++i) { int v = scnt[i]; scnt[i] = acc; acc += v; }
        }
        __syncthreads();
        if (t < 51) hhoff[b*64 + t] = (t < H_) ? scnt[t] : EHH_;
        __syncthreads();
        for (int e = t; e < EHH_; e += 256) {
            int r = srow[e];
            int pos = atomicAdd(&scnt[r], 1);
            hhcol[b*EHH_ + pos] = scol[e];
            hhem [b*EHH_ + pos] = sem[e];
        }
        return;
    }
    blk -= SORT_BLKS_;
    if (blk < HROW_BLKS_) {
        // h-node layer-0 projections; fold b1 and t*w160 into hiW1
        int g = blk*256 + t;                 // [0, 51200)
        int node = g >> 7, col = g & 127;    // node = b*H + h
        int b = node / H_;
        int label = lab_h[node], pos = pos_h[node];
        int aa = pep[b*15 + pos - 1];
        const float* W1l = W1;               // layer 0
        float hi = W1l[label*HID_ + col]
                 + W1l[(44 + aa)*HID_ + col]
                 + W1l[(64 + pos - 1)*HID_ + col]
                 + b1[col]
                 + t_in[b] * W1l[160*HID_ + col];
        float hj = W1l[(FDIM_ + label)*HID_ + col]
                 + W1l[(FDIM_ + 44 + aa)*HID_ + col]
                 + W1l[(FDIM_ + 64 + pos - 1)*HID_ + col];
        int h = node % H_;
        #pragma unroll
        for (int s = 0; s < S_; ++s) {
            int row = (b*S_ + s)*H_ + h;
            hiW1[(size_t)row*HID_ + col] = hi;
            hjW1[(size_t)row*HID_ + col] = hj;
        }
        return;
    }
    blk -= HROW_BLKS_;
    if (blk < FEAT_BLKS_) {
        int g = blk*256 + t;                 // [0, 32000)
        int node = g / FS_, f = g % FS_;     // node = b*H + h
        int b = node / H_, h = node % H_;
        int label = lab_h[node], pos = pos_h[node];
        int aa = pep[b*15 + pos - 1];
        float v = 0.f;
        if (f < 44)      v = (f == label)          ? 1.0f : 0.0f;
        else if (f < 64) v = ((f - 44) == aa)      ? 1.0f : 0.0f;
        else if (f < 79) v = ((f - 64) == pos - 1) ? 1.0f : 0.0f;
        #pragma unroll
        for (int s = 0; s < S_; ++s)
            feat_h[((b*S_ + s)*H_ + h)*FS_ + f] = v;
        return;
    }
    blk -= FEAT_BLKS_;
    {
        int g = blk*256 + t;
        if (g >= BS_*NN_) return;
        int bs = g / NN_, n = g % NN_;
        int b = bs / S_;
        if (n < H_) {
            int ba = bound[b*H_ + n];
            for (int d = 0; d < 3; ++d) {
                float v = x_h[(bs*H_ + n)*3 + d] + x_hv[(b*NH_ + ba)*3 + d];
                x[g*4 + d] = v;
                x0h[(bs*H_ + n)*4 + d] = v;
            }
        } else {
            int nh = n - H_;
            for (int d = 0; d < 3; ++d) x[g*4 + d] = x_hv[(b*NH_ + nh)*3 + d];
        }
    }
}

// ============ per-layer: one block per output row; MFMA edge MLP, register aggregation ============
// Each wave independently processes 16-edge tiles (ti = w, w+4, ...) of this row's
// edge list (cnt_hh sorted hh edges + 200 grid edges). All per-tile LDS is
// wave-private (wave_barrier ordering). aggm/aggx accumulate in registers;
// single cross-wave combine + direct store.
// Occupancy control (Round 2/3 post-mortems): no bound -> 248 VGPR (2 waves/SIMD,
// latency-bound); __launch_bounds__(256,3) (min-only) -> LLVM chased 6 waves/EU,
// 84 VGPR + 950 MB scratch spills. amdgpu_waves_per_eu(3,3) pins BOTH min and max:
// hard ~170-VGPR budget, no incentive to spill below it.
__global__ __launch_bounds__(256)
__attribute__((amdgpu_waves_per_eu(3, 3)))
void k_edge_mlp(
    const float* __restrict__ x, const float* __restrict__ hiW1,
    const float* __restrict__ hjW1,
    const int* __restrict__ hhcol, const float* __restrict__ hhem,
    const int* __restrict__ hhoff,
    const float* __restrict__ em_hv, const float* __restrict__ bond_in,
    const float* __restrict__ W1,
    const float* __restrict__ b2, const float* __restrict__ bc1,
    const float* __restrict__ Wc2,
    const unsigned short* __restrict__ Wp, int l,
    float* __restrict__ aggx, float* __restrict__ aggm)
{
    __shared__ unsigned short s_m[4][16][MSTR_];   // 17408 B, wave-private 16-row chunks
    __shared__ float s_es[4][16][6];               // diff0..2, dist, bond, emk
    __shared__ int   s_jj[4][16];
    __shared__ float s_c[6][HID_];                 // hi, W1r158, W1r159, b2, bc1, Wc2
    __shared__ float s_mr[4][HID_];
    __shared__ float s_xr[4][4];

    const int t = threadIdx.x, lane = t & 63, w = t >> 6;
    const int l15 = lane & 15, q = lane >> 4;
    const int node = blockIdx.x;                   // bs*H + h
    const int bs = node / H_, h = node - bs*H_;
    const int b = bs / S_;

    const float* W1l = W1 + l*EDIM_*HID_;
    if (t < HID_) {
        s_c[0][t] = hiW1[(size_t)node*HID_ + t];
        s_c[1][t] = W1l[158*HID_ + t];
        s_c[2][t] = W1l[159*HID_ + t];
        s_c[3][t] = b2 [l*HID_ + t];
        s_c[4][t] = bc1[l*HID_ + t];
        s_c[5][t] = Wc2[l*HID_ + t];
    }

    const int hh0 = hhoff[b*64 + h];
    const int cnt = hhoff[b*64 + h + 1] - hh0;
    const int E   = cnt + NH_;                     // total real edges for this row
    const int NT  = (E + 15) >> 4;                 // 16-edge tiles

    const float xi0 = x[(bs*NN_ + h)*4 + 0];
    const float xi1 = x[(bs*NN_ + h)*4 + 1];
    const float xi2 = x[(bs*NN_ + h)*4 + 2];

    float macc[8] = {0.f,0.f,0.f,0.f,0.f,0.f,0.f,0.f};
    float xacc = 0.f;
    const unsigned short* Wp2 = Wp + (size_t)(l*2 + 0)*16384;
    const unsigned short* Wp3 = Wp + (size_t)(l*2 + 1)*16384;
    __syncthreads();                               // s_c ready

    for (int ti = w; ti < NT; ti += 4) {
        // ---- per-edge scalars for this wave's 16 edges ----
        if (lane < 16) {
            int e = ti*16 + lane;
            float d0=0.f,d1=0.f,d2=0.f,dist=0.f,bnd=0.f,em=0.f;
            int jj = bs*H_;                        // padding: valid row, em=0, diff=0
            if (e < E) {
                int col;
                if (e < cnt) {                     // sorted hh edge
                    col = hhcol[b*EHH_ + hh0 + e];
                    em  = hhem [b*EHH_ + hh0 + e];
                    jj  = bs*H_ + col;
                } else {                           // grid edge (row h -> heavy cc)
                    int cc = e - cnt;
                    col = H_ + cc;
                    em  = em_hv [(b*H_ + h)*NH_ + cc];
                    bnd = bond_in[(b*H_ + h)*NH_ + cc];
                    jj  = HVB_ + l*1600 + b*NH_ + cc;
                }
                d0 = xi0 - x[(bs*NN_ + col)*4 + 0];
                d1 = xi1 - x[(bs*NN_ + col)*4 + 1];
                d2 = xi2 - x[(bs*NN_ + col)*4 + 2];
                dist = sqrtf(d0*d0 + d1*d1 + d2*d2);
            }
            s_es[w][lane][0] = d0; s_es[w][lane][1] = d1; s_es[w][lane][2] = d2;
            s_es[w][lane][3] = dist; s_es[w][lane][4] = bnd; s_es[w][lane][5] = em;
            s_jj[w][lane] = jj;
        }
        __builtin_amdgcn_wave_barrier();

        // ---- stage 1: m1 = silu(hi + hj + dist*w158 + bond*w159) ----
        const float dist = s_es[w][l15][3];
        const float bnd  = s_es[w][l15][4];
        const int   jj   = s_jj[w][l15];
        const float* pj  = hjW1 + (size_t)jj*HID_ + q*8;
        short8 afrag[4];
        #pragma unroll
        for (int kc = 0; kc < 4; ++kc) {
            int k0 = kc*32 + q*8;
            float4 c0 = *(const float4*)(pj + kc*32);
            float4 c1 = *(const float4*)(pj + kc*32 + 4);
            float4 h0 = *(const float4*)&s_c[0][k0];
            float4 h1 = *(const float4*)&s_c[0][k0 + 4];
            float4 wa0= *(const float4*)&s_c[1][k0];
            float4 wa1= *(const float4*)&s_c[1][k0 + 4];
            float4 wb0= *(const float4*)&s_c[2][k0];
            float4 wb1= *(const float4*)&s_c[2][k0 + 4];
            short8 fr;
            fr[0] = (short)f2bf(silu_(h0.x + c0.x + dist*wa0.x + bnd*wb0.x));
            fr[1] = (short)f2bf(silu_(h0.y + c0.y + dist*wa0.y + bnd*wb0.y));
            fr[2] = (short)f2bf(silu_(h0.z + c0.z + dist*wa0.z + bnd*wb0.z));
            fr[3] = (short)f2bf(silu_(h0.w + c0.w + dist*wa0.w + bnd*wb0.w));
            fr[4] = (short)f2bf(silu_(h1.x + c1.x + dist*wa1.x + bnd*wb1.x));
            fr[5] = (short)f2bf(silu_(h1.y + c1.y + dist*wa1.y + bnd*wb1.y));
            fr[6] = (short)f2bf(silu_(h1.z + c1.z + dist*wa1.z + bnd*wb1.z));
            fr[7] = (short)f2bf(silu_(h1.w + c1.w + dist*wa1.w + bnd*wb1.w));
            afrag[kc] = fr;
        }

        // ---- stage 2: m = silu(m1 @ W2 + b2) * emask; accumulate column sums ----
        // NOTE: nt loop must stay FULLY unrolled — macc[nt] needs a compile-time
        // index (rule #20: runtime-indexed register arrays go to scratch).
        float em4[4];
        #pragma unroll
        for (int r = 0; r < 4; ++r) em4[r] = s_es[w][q*4 + r][5];
        #pragma unroll
        for (int nt = 0; nt < 8; ++nt) {
            float bias = s_c[3][nt*16 + l15];
            f32x4 c = {bias, bias, bias, bias};
            #pragma unroll
            for (int kc = 0; kc < 4; ++kc) {
                short8 bf = *(const short8*)&Wp2[(size_t)((kc*128 + nt*16 + l15)*4 + q)*8];
                c = __builtin_amdgcn_mfma_f32_16x16x32_bf16(afrag[kc], bf, c, 0, 0, 0);
            }
            #pragma unroll
            for (int r = 0; r < 4; ++r) {
                float mv = silu_(c[r]) * em4[r];   // padding edges have em=0 -> mv=0
                s_m[w][q*4 + r][nt*16 + l15] = f2bf(mv);
                macc[nt] += mv;
            }
        }
        __builtin_amdgcn_wave_barrier();

        // ---- stage 3: cw = silu(m @ Wc1 + bc1) @ Wc2; accumulate diff*cw ----
        // unroll 2 is safe here (p[r]/af2[kc] indices stay compile-time) and
        // halves the hoisted B-fragment transients.
        short8 af2[4];
        #pragma unroll
        for (int kc = 0; kc < 4; ++kc)
            af2[kc] = *(const short8*)&s_m[w][l15][kc*32 + q*8];
        float p[4] = {0.f, 0.f, 0.f, 0.f};
        #pragma unroll 2
        for (int nt = 0; nt < 8; ++nt) {
            float bias = s_c[4][nt*16 + l15];
            f32x4 c = {bias, bias, bias, bias};
            #pragma unroll
            for (int kc = 0; kc < 4; ++kc) {
                short8 bf = *(const short8*)&Wp3[(size_t)((kc*128 + nt*16 + l15)*4 + q)*8];
                c = __builtin_amdgcn_mfma_f32_16x16x32_bf16(af2[kc], bf, c, 0, 0, 0);
            }
            float wcv = s_c[5][nt*16 + l15];
            #pragma unroll
            for (int r = 0; r < 4; ++r)
                p[r] += silu_(c[r]) * wcv;
        }
        // reduce p over the 16 l15-lanes of this q-group -> cw per edge q*4+r
        #pragma unroll
        for (int m = 1; m < 16; m <<= 1) {
            #pragma unroll
            for (int r = 0; r < 4; ++r) p[r] += __shfl_xor(p[r], m, 64);
        }
        if (l15 < 3) {                              // lane d=l15 accumulates dim d
            #pragma unroll
            for (int r = 0; r < 4; ++r)
                xacc += s_es[w][q*4 + r][l15] * p[r];   // padding: diff=0
        }
        __builtin_amdgcn_wave_barrier();
    }

    // ---- cross-q, cross-wave combine; direct stores (no atomics, no pre-zero) ----
    #pragma unroll
    for (int nt = 0; nt < 8; ++nt) {
        macc[nt] += __shfl_xor(macc[nt], 16, 64);
        macc[nt] += __shfl_xor(macc[nt], 32, 64);
    }
    if (q == 0) {
        #pragma unroll
        for (int nt = 0; nt < 8; ++nt) s_mr[w][nt*16 + l15] = macc[nt];
    }
    xacc += __shfl_xor(xacc, 16, 64);
    xacc += __shfl_xor(xacc, 32, 64);
    if (q == 0 && l15 < 3) s_xr[w][l15] = xacc;
    __syncthreads();
    if (t < HID_) {
        aggm[(size_t)node*HID_ + t] = s_mr[0][t] + s_mr[1][t] + s_mr[2][t] + s_mr[3][t];
    } else if (t < HID_ + 3) {
        int d = t - HID_;
        aggx[node*4 + d] = s_xr[0][d] + s_xr[1][d] + s_xr[2][d] + s_xr[3][d];
    }
}

// ====== per-layer: node update (8 nodes/block) + next-layer W1 (folded) + out ======
__global__ __launch_bounds__(128) void k_update(
    float* __restrict__ feat_h, float* __restrict__ x,
    const float* __restrict__ aggm, const float* __restrict__ aggx,
    const float* __restrict__ Wn1, const float* __restrict__ bn1,
    const float* __restrict__ Wn2, const float* __restrict__ bn2, int l,
    const float* __restrict__ W1, const float* __restrict__ b1,
    const float* __restrict__ t_in,
    float* __restrict__ hiW1, float* __restrict__ hjW1, int do_w1,
    const float* __restrict__ x0h, const float* __restrict__ amask,
    float* __restrict__ out)
{
    __shared__ float s_in[8][NDIM_ + 1];
    __shared__ float s_u[8][HID_ + 1];
    int node0 = blockIdx.x * 8;            // bs*H + h
    int t = threadIdx.x;
    for (int idx = t; idx < 8*(NDIM_ + 1); idx += 128) {
        int g = idx / (NDIM_ + 1), k = idx % (NDIM_ + 1);
        float v = 0.f;
        if (k < FDIM_)      v = feat_h[(node0 + g)*FS_ + k];
        else if (k < NDIM_) v = aggm[(size_t)(node0 + g)*HID_ + (k - FDIM_)];
        s_in[g][k] = v;
    }
    __syncthreads();
    const float* Wn1l = Wn1 + l*NDIM_*HID_;
    float acc[8];
    float bv = bn1[l*HID_ + t];
    #pragma unroll
    for (int g = 0; g < 8; ++g) acc[g] = bv;
    for (int k = 0; k < NDIM_; ++k) {
        float wv = Wn1l[k*HID_ + t];
        #pragma unroll
        for (int g = 0; g < 8; ++g) acc[g] += s_in[g][k] * wv;
    }
    #pragma unroll
    for (int g = 0; g < 8; ++g) s_u[g][t] = silu_(acc[g]);
    __syncthreads();
    if (t < FDIM_) {
        const float* Wn2l = Wn2 + l*HID_*FDIM_;
        float acc2[8];
        float b2v = bn2[l*FDIM_ + t];
        #pragma unroll
        for (int g = 0; g < 8; ++g) acc2[g] = b2v;
        for (int k = 0; k < HID_; ++k) {
            float wv = Wn2l[k*FDIM_ + t];
            #pragma unroll
            for (int g = 0; g < 8; ++g) acc2[g] += s_u[g][k] * wv;
        }
        #pragma unroll
        for (int g = 0; g < 8; ++g) {
            float nf = s_in[g][t] + acc2[g];
            feat_h[(node0 + g)*FS_ + t] = nf;
            s_in[g][t] = nf;
        }
    } else if (t >= 96 && t < 120) {
        int idx = t - 96, g = idx / 3, d = idx % 3;
        int node = node0 + g;
        int bs = node / H_, h = node % H_;
        float xv = x[(bs*NN_ + h)*4 + d] + aggx[node*4 + d];
        x[(bs*NN_ + h)*4 + d] = xv;
        if (!do_w1) {
            int b = bs / S_;
            out[node*3 + d] = (xv - x0h[node*4 + d]) * amask[b*H_ + h];
        }
    }
    if (!do_w1) return;
    __syncthreads();
    // ---- next-layer W1 projections (fold b1 + t*w160 into hiW1) ----
    {
        const float* W1n = W1 + (l + 1)*EDIM_*HID_;
        float w160 = W1n[160*HID_ + t];
        float b1v  = b1[(l + 1)*HID_ + t];
        float hia[8], hja[8];
        #pragma unroll
        for (int g = 0; g < 8; ++g) { hia[g] = 0.f; hja[g] = 0.f; }
        for (int f = 0; f < FDIM_; ++f) {
            float wi = W1n[f*HID_ + t];
            float wj = W1n[(FDIM_ + f)*HID_ + t];
            #pragma unroll
            for (int g = 0; g < 8; ++g) {
                float v = s_in[g][f];
                hia[g] += v * wi;
                hja[g] += v * wj;
            }
        }
        #pragma unroll
        for (int g = 0; g < 8; ++g) {
            int node = node0 + g;
            int b = (node / H_) / S_;
            hiW1[(size_t)node*HID_ + t] = hia[g] + b1v + t_in[b]*w160;
            hjW1[(size_t)node*HID_ + t] = hja[g];
        }
    }
}

// ---------------- launch ----------------
extern "C" void kernel_launch(void* const* d_in, const int* in_sizes, int n_in,
                              void* d_out, int out_size, void* d_ws, size_t ws_size,
                              hipStream_t stream)
{
    const float* t_in  = (const float*)d_in[0];
    const float* x_h   = (const float*)d_in[1];
    const float* x_hv  = (const float*)d_in[2];
    const float* bond  = (const float*)d_in[3];
    const float* em_hv = (const float*)d_in[4];
    const float* em_hh = (const float*)d_in[5];
    const float* amask = (const float*)d_in[6];
    const float* W1    = (const float*)d_in[7];
    const float* b1    = (const float*)d_in[8];
    const float* W2    = (const float*)d_in[9];
    const float* b2    = (const float*)d_in[10];
    const float* Wc1   = (const float*)d_in[11];
    const float* bc1   = (const float*)d_in[12];
    const float* Wc2   = (const float*)d_in[13];
    const float* Wn1   = (const float*)d_in[14];
    const float* bn1   = (const float*)d_in[15];
    const float* Wn2   = (const float*)d_in[16];
    const float* bn2   = (const float*)d_in[17];
    const int* pep     = (const int*)d_in[18];
    const int* lab_hv  = (const int*)d_in[19];
    const int* lab_h   = (const int*)d_in[20];
    const int* pos_hv  = (const int*)d_in[21];
    const int* pos_h   = (const int*)d_in[22];
    const int* ehh     = (const int*)d_in[23];
    const int* bound   = (const int*)d_in[24];

    float* ws     = (float*)d_ws;
    float* feat_h = ws + OFF_FEATH;
    float* x      = ws + OFF_X;
    float* x0h    = ws + OFF_X0H;
    int*   hhcol  = (int*)(ws + OFF_HHCOL);
    float* hhem   = ws + OFF_HHEM;
    int*   hhoff  = (int*)(ws + OFF_HHOFF);
    float* hiW1   = ws + OFF_HIW1;
    float* hjW1   = ws + OFF_HJW1;
    unsigned short* Wp = (unsigned short*)(ws + OFF_WP);

    hipLaunchKernelGGL(k_setup, dim3(SETUP_BLKS_), dim3(256), 0, stream,
                       x_h, x_hv, bound, ehh, em_hh,
                       W1, b1, t_in, W2, Wc1,
                       lab_h, pos_h, lab_hv, pos_hv, pep,
                       feat_h, x, x0h, hhcol, hhem, hhoff,
                       hiW1, hjW1, Wp);

    for (int l = 0; l < L_; ++l) {
        float* aggx_l = ws + OFF_AGG0 + (size_t)l*AGGSTRIDE_;
        float* aggm_l = aggx_l + 6400;
        hipLaunchKernelGGL(k_edge_mlp, dim3(NROW_), dim3(256), 0, stream,
                           x, hiW1, hjW1, hhcol, hhem, hhoff, em_hv, bond,
                           W1, b2, bc1, Wc2, Wp, l, aggx_l, aggm_l);
        int do_w1 = (l == 0);
        hipLaunchKernelGGL(k_update, dim3(200), dim3(128), 0, stream,
                           feat_h, x, aggm_l, aggx_l, Wn1, bn1, Wn2, bn2, l,
                           W1, b1, t_in, hiW1, hjW1, do_w1,
                           x0h, amask, (float*)d_out);
    }
}

// Round 5
// 644.479 us; speedup vs baseline: 1.2825x; 1.0020x over previous
//
#include <hip/hip_runtime.h>
#include <math.h>

// Problem constants
#define B_     8
#define S_     4
#define H_     50
#define NH_    200
#define EHH_   400
#define L_     2
#define HID_   128
#define FDIM_  79          // 44 + 20 + 15
#define EDIM_  161         // 2*FDIM + 3
#define NN_    250         // H + NH
#define BS_    32          // B*S
#define NROW_  1600        // BS*H (one block per output row in edge kernel)
#define FS_    80          // feat row stride
#define MSTR_  136         // s_m stride in bf16 (128 + 8)
#define NDIM_  207         // FDIM + HID
#define HVB_   1600        // hjW1 heavy-region base row

// Workspace layout (float offsets)
#define OFF_FEATH  0         // BS*H*80 = 128000
#define OFF_X      128000    // BS*NN*4 = 32000
#define OFF_X0H    160000    // 6400
#define OFF_HHCOL  166400    // 3200 (int)  sorted hh cols, 400 per b
#define OFF_HHEM   169600    // 3200        sorted hh edge masks
#define OFF_HHOFF  172800    // 512 (int)   CSR row offsets, 64 per b (0..50 used)
#define OFF_AGG0   173312    // aggx(6400) + aggm(204800) = 211200
#define AGGSTRIDE_ 211200
#define OFF_AGG1   384512
#define OFF_HIW1   595712    // fp32 1600*128 (b1 + t*w160 folded in)
#define OFF_HJW1   800512    // fp32 4800*128: [0,1600) h cur | [1600,3200) hv l0 | [3200,4800) hv l1
#define OFF_WP     1414912   // 65536 ushort

typedef __attribute__((ext_vector_type(8))) short short8;
typedef __attribute__((ext_vector_type(4))) float f32x4;

__device__ __forceinline__ float silu_(float v) {
    return v * __builtin_amdgcn_rcpf(1.0f + __expf(-v));
}
__device__ __forceinline__ unsigned short f2bf(float f) {
    unsigned int u = __float_as_uint(f);
    unsigned int r = (u + 0x7fffu + ((u >> 16) & 1u)) >> 16;
    return (unsigned short)r;
}

// ================= fused setup =================
#define HV_BLKS_    1600   // heavy hjW1 both layers: 409600
#define PACK_BLKS_  256    // 65536
#define SORT_BLKS_  8      // counting-sort hh edges by row, per b; emits CSR
#define HROW_BLKS_  200    // 400*128
#define FEAT_BLKS_  125    // 400*80
#define XI_BLKS_    32     // 8000
#define SETUP_BLKS_ (HV_BLKS_ + PACK_BLKS_ + SORT_BLKS_ + HROW_BLKS_ + FEAT_BLKS_ + XI_BLKS_)

__global__ __launch_bounds__(256) void k_setup(
    const float* __restrict__ x_h, const float* __restrict__ x_hv,
    const int* __restrict__ bound,
    const int* __restrict__ ehh, const float* __restrict__ em_hh,
    const float* __restrict__ W1, const float* __restrict__ b1,
    const float* __restrict__ t_in,
    const float* __restrict__ W2, const float* __restrict__ Wc1,
    const int* __restrict__ lab_h, const int* __restrict__ pos_h,
    const int* __restrict__ lab_hv, const int* __restrict__ pos_hv,
    const int* __restrict__ pep,
    float* __restrict__ feat_h,
    float* __restrict__ x, float* __restrict__ x0h,
    int* __restrict__ hhcol, float* __restrict__ hhem, int* __restrict__ hhoff,
    float* __restrict__ hiW1, float* __restrict__ hjW1,
    unsigned short* __restrict__ Wp)
{
    int blk = blockIdx.x, t = threadIdx.x;
    if (blk < HV_BLKS_) {
        int g = blk*256 + t;                 // [0, 409600)
        int l = g / 204800;
        int r = g - l*204800;
        int node = r >> 7, col = r & 127;    // node = b*NH + nh
        int b = node / NH_;
        int label = lab_hv[node], pos = pos_hv[node];
        int aa = pep[b*15 + pos - 1];
        const float* W1l = W1 + l*EDIM_*HID_;
        float hj = W1l[(FDIM_ + label)*HID_ + col]
                 + W1l[(FDIM_ + 44 + aa)*HID_ + col]
                 + W1l[(FDIM_ + 64 + pos - 1)*HID_ + col];
        hjW1[(size_t)(HVB_ + l*1600 + node)*HID_ + col] = hj;
        return;
    }
    blk -= HV_BLKS_;
    if (blk < PACK_BLKS_) {
        int g = blk*256 + t;
        int idx = g & 16383;
        int lm  = g >> 14;
        int l = lm >> 1, mat = lm & 1;
        int j = idx & 7, q = (idx >> 3) & 3, n = (idx >> 5) & 127, kc = idx >> 12;
        int k = kc*32 + q*8 + j;
        const float* W = (mat == 0 ? W2 : Wc1) + l*HID_*HID_;
        Wp[g] = f2bf(W[k*HID_ + n]);
        return;
    }
    blk -= PACK_BLKS_;
    if (blk < SORT_BLKS_) {
        // counting-sort the 400 hh edges of batch b by row; emit CSR offsets
        int b = blk;
        __shared__ int scnt[64];
        __shared__ int srow[EHH_], scol[EHH_];
        __shared__ float sem[EHH_];
        if (t < 64) scnt[t] = 0;
        __syncthreads();
        for (int e = t; e < EHH_; e += 256) {
            int r = ehh[(b*EHH_ + e)*2 + 0];
            srow[e] = r;
            scol[e] = ehh[(b*EHH_ + e)*2 + 1];
            sem[e]  = em_hh[b*EHH_ + e];
            atomicAdd(&scnt[r], 1);
        }
        __syncthreads();
        if (t == 0) {
            int acc = 0;
            for (int i = 0; i < H_; ++i) { int v = scnt[i]; scnt[i] = acc; acc += v; }
        }
        __syncthreads();
        if (t < 51) hhoff[b*64 + t] = (t < H_) ? scnt[t] : EHH_;
        __syncthreads();
        for (int e = t; e < EHH_; e += 256) {
            int r = srow[e];
            int pos = atomicAdd(&scnt[r], 1);
            hhcol[b*EHH_ + pos] = scol[e];
            hhem [b*EHH_ + pos] = sem[e];
        }
        return;
    }
    blk -= SORT_BLKS_;
    if (blk < HROW_BLKS_) {
        // h-node layer-0 projections; fold b1 and t*w160 into hiW1
        int g = blk*256 + t;                 // [0, 51200)
        int node = g >> 7, col = g & 127;    // node = b*H + h
        int b = node / H_;
        int label = lab_h[node], pos = pos_h[node];
        int aa = pep[b*15 + pos - 1];
        const float* W1l = W1;               // layer 0
        float hi = W1l[label*HID_ + col]
                 + W1l[(44 + aa)*HID_ + col]
                 + W1l[(64 + pos - 1)*HID_ + col]
                 + b1[col]
                 + t_in[b] * W1l[160*HID_ + col];
        float hj = W1l[(FDIM_ + label)*HID_ + col]
                 + W1l[(FDIM_ + 44 + aa)*HID_ + col]
                 + W1l[(FDIM_ + 64 + pos - 1)*HID_ + col];
        int h = node % H_;
        #pragma unroll
        for (int s = 0; s < S_; ++s) {
            int row = (b*S_ + s)*H_ + h;
            hiW1[(size_t)row*HID_ + col] = hi;
            hjW1[(size_t)row*HID_ + col] = hj;
        }
        return;
    }
    blk -= HROW_BLKS_;
    if (blk < FEAT_BLKS_) {
        int g = blk*256 + t;                 // [0, 32000)
        int node = g / FS_, f = g % FS_;     // node = b*H + h
        int b = node / H_, h = node % H_;
        int label = lab_h[node], pos = pos_h[node];
        int aa = pep[b*15 + pos - 1];
        float v = 0.f;
        if (f < 44)      v = (f == label)          ? 1.0f : 0.0f;
        else if (f < 64) v = ((f - 44) == aa)      ? 1.0f : 0.0f;
        else if (f < 79) v = ((f - 64) == pos - 1) ? 1.0f : 0.0f;
        #pragma unroll
        for (int s = 0; s < S_; ++s)
            feat_h[((b*S_ + s)*H_ + h)*FS_ + f] = v;
        return;
    }
    blk -= FEAT_BLKS_;
    {
        int g = blk*256 + t;
        if (g >= BS_*NN_) return;
        int bs = g / NN_, n = g % NN_;
        int b = bs / S_;
        if (n < H_) {
            int ba = bound[b*H_ + n];
            for (int d = 0; d < 3; ++d) {
                float v = x_h[(bs*H_ + n)*3 + d] + x_hv[(b*NH_ + ba)*3 + d];
                x[g*4 + d] = v;
                x0h[(bs*H_ + n)*4 + d] = v;
            }
        } else {
            int nh = n - H_;
            for (int d = 0; d < 3; ++d) x[g*4 + d] = x_hv[(b*NH_ + nh)*3 + d];
        }
    }
}

// ============ per-layer: one block per output row; MFMA edge MLP, register aggregation ============
// Each wave independently processes 16-edge tiles (ti = w, w+4, ...) of this row's
// edge list (cnt_hh sorted hh edges + 200 grid edges). All per-tile LDS is
// wave-private (wave_barrier ordering). aggm/aggx accumulate in registers;
// single cross-wave combine + direct store.
//
// Occupancy control history:
//   R2: no bound -> 248 VGPR, 2 waves/EU, no spill, 166 us (latency-bound).
//   R3: __launch_bounds__(256,3) -> scheduler chased the LDS-permitted 6 waves/EU
//       (static LDS 24.6KB -> 6 blk/CU), budget 85 VGPR, 950 MB scratch spills.
//   R4: amdgpu_waves_per_eu(3,3) NOT honored -> identical 84 VGPR + spills.
// Fix: control the scheduler's occupancy target through the LDS limit itself.
// s_pad pushes static LDS to ~49 KB -> exactly 3 blocks/CU -> RA budget ~168 VGPR
// >= loop min-pressure (~130) -> no spill, deterministically.
__global__ __launch_bounds__(256) void k_edge_mlp(
    const float* __restrict__ x, const float* __restrict__ hiW1,
    const float* __restrict__ hjW1,
    const int* __restrict__ hhcol, const float* __restrict__ hhem,
    const int* __restrict__ hhoff,
    const float* __restrict__ em_hv, const float* __restrict__ bond_in,
    const float* __restrict__ W1,
    const float* __restrict__ b2, const float* __restrict__ bc1,
    const float* __restrict__ Wc2,
    const unsigned short* __restrict__ Wp, int l,
    float* __restrict__ aggx, float* __restrict__ aggm)
{
    __shared__ unsigned short s_m[4][16][MSTR_];   // 17408 B, wave-private 16-row chunks
    __shared__ float s_es[4][16][6];               // diff0..2, dist, bond, emk
    __shared__ int   s_jj[4][16];
    __shared__ float s_c[6][HID_];                 // hi, W1r158, W1r159, b2, bc1, Wc2
    __shared__ float s_mr[4][HID_];
    __shared__ float s_xr[4][4];
    __shared__ float s_pad[6144];                  // 24576 B occupancy shaper (see header)

    const int t = threadIdx.x, lane = t & 63, w = t >> 6;
    const int l15 = lane & 15, q = lane >> 4;
    const int node = blockIdx.x;                   // bs*H + h
    const int bs = node / H_, h = node - bs*H_;
    const int b = bs / S_;

    // keepalive for s_pad: hhoff[0] is the CSR start of batch-0 row-0 == 0 always,
    // but the compiler cannot prove it, so s_pad cannot be eliminated.
    if (hhoff[0] != 0) {
        s_pad[t] = (float)t;
        __syncthreads();                           // block-uniform condition: legal
        aggx[t] = s_pad[255 - t];
    }

    const float* W1l = W1 + l*EDIM_*HID_;
    if (t < HID_) {
        s_c[0][t] = hiW1[(size_t)node*HID_ + t];
        s_c[1][t] = W1l[158*HID_ + t];
        s_c[2][t] = W1l[159*HID_ + t];
        s_c[3][t] = b2 [l*HID_ + t];
        s_c[4][t] = bc1[l*HID_ + t];
        s_c[5][t] = Wc2[l*HID_ + t];
    }

    const int hh0 = hhoff[b*64 + h];
    const int cnt = hhoff[b*64 + h + 1] - hh0;
    const int E   = cnt + NH_;                     // total real edges for this row
    const int NT  = (E + 15) >> 4;                 // 16-edge tiles

    const float xi0 = x[(bs*NN_ + h)*4 + 0];
    const float xi1 = x[(bs*NN_ + h)*4 + 1];
    const float xi2 = x[(bs*NN_ + h)*4 + 2];

    float macc[8] = {0.f,0.f,0.f,0.f,0.f,0.f,0.f,0.f};
    float xacc = 0.f;
    const unsigned short* Wp2 = Wp + (size_t)(l*2 + 0)*16384;
    const unsigned short* Wp3 = Wp + (size_t)(l*2 + 1)*16384;
    __syncthreads();                               // s_c ready

    for (int ti = w; ti < NT; ti += 4) {
        // ---- per-edge scalars for this wave's 16 edges ----
        if (lane < 16) {
            int e = ti*16 + lane;
            float d0=0.f,d1=0.f,d2=0.f,dist=0.f,bnd=0.f,em=0.f;
            int jj = bs*H_;                        // padding: valid row, em=0, diff=0
            if (e < E) {
                int col;
                if (e < cnt) {                     // sorted hh edge
                    col = hhcol[b*EHH_ + hh0 + e];
                    em  = hhem [b*EHH_ + hh0 + e];
                    jj  = bs*H_ + col;
                } else {                           // grid edge (row h -> heavy cc)
                    int cc = e - cnt;
                    col = H_ + cc;
                    em  = em_hv [(b*H_ + h)*NH_ + cc];
                    bnd = bond_in[(b*H_ + h)*NH_ + cc];
                    jj  = HVB_ + l*1600 + b*NH_ + cc;
                }
                d0 = xi0 - x[(bs*NN_ + col)*4 + 0];
                d1 = xi1 - x[(bs*NN_ + col)*4 + 1];
                d2 = xi2 - x[(bs*NN_ + col)*4 + 2];
                dist = sqrtf(d0*d0 + d1*d1 + d2*d2);
            }
            s_es[w][lane][0] = d0; s_es[w][lane][1] = d1; s_es[w][lane][2] = d2;
            s_es[w][lane][3] = dist; s_es[w][lane][4] = bnd; s_es[w][lane][5] = em;
            s_jj[w][lane] = jj;
        }
        __builtin_amdgcn_wave_barrier();

        // ---- stage 1: m1 = silu(hi + hj + dist*w158 + bond*w159) ----
        const float dist = s_es[w][l15][3];
        const float bnd  = s_es[w][l15][4];
        const int   jj   = s_jj[w][l15];
        const float* pj  = hjW1 + (size_t)jj*HID_ + q*8;
        short8 afrag[4];
        #pragma unroll
        for (int kc = 0; kc < 4; ++kc) {
            int k0 = kc*32 + q*8;
            float4 c0 = *(const float4*)(pj + kc*32);
            float4 c1 = *(const float4*)(pj + kc*32 + 4);
            float4 h0 = *(const float4*)&s_c[0][k0];
            float4 h1 = *(const float4*)&s_c[0][k0 + 4];
            float4 wa0= *(const float4*)&s_c[1][k0];
            float4 wa1= *(const float4*)&s_c[1][k0 + 4];
            float4 wb0= *(const float4*)&s_c[2][k0];
            float4 wb1= *(const float4*)&s_c[2][k0 + 4];
            short8 fr;
            fr[0] = (short)f2bf(silu_(h0.x + c0.x + dist*wa0.x + bnd*wb0.x));
            fr[1] = (short)f2bf(silu_(h0.y + c0.y + dist*wa0.y + bnd*wb0.y));
            fr[2] = (short)f2bf(silu_(h0.z + c0.z + dist*wa0.z + bnd*wb0.z));
            fr[3] = (short)f2bf(silu_(h0.w + c0.w + dist*wa0.w + bnd*wb0.w));
            fr[4] = (short)f2bf(silu_(h1.x + c1.x + dist*wa1.x + bnd*wb1.x));
            fr[5] = (short)f2bf(silu_(h1.y + c1.y + dist*wa1.y + bnd*wb1.y));
            fr[6] = (short)f2bf(silu_(h1.z + c1.z + dist*wa1.z + bnd*wb1.z));
            fr[7] = (short)f2bf(silu_(h1.w + c1.w + dist*wa1.w + bnd*wb1.w));
            afrag[kc] = fr;
        }

        // ---- stage 2: m = silu(m1 @ W2 + b2) * emask; accumulate column sums ----
        // NOTE: nt loop must stay FULLY unrolled — macc[nt] needs a compile-time
        // index (rule #20: runtime-indexed register arrays go to scratch).
        float em4[4];
        #pragma unroll
        for (int r = 0; r < 4; ++r) em4[r] = s_es[w][q*4 + r][5];
        #pragma unroll
        for (int nt = 0; nt < 8; ++nt) {
            float bias = s_c[3][nt*16 + l15];
            f32x4 c = {bias, bias, bias, bias};
            #pragma unroll
            for (int kc = 0; kc < 4; ++kc) {
                short8 bf = *(const short8*)&Wp2[(size_t)((kc*128 + nt*16 + l15)*4 + q)*8];
                c = __builtin_amdgcn_mfma_f32_16x16x32_bf16(afrag[kc], bf, c, 0, 0, 0);
            }
            #pragma unroll
            for (int r = 0; r < 4; ++r) {
                float mv = silu_(c[r]) * em4[r];   // padding edges have em=0 -> mv=0
                s_m[w][q*4 + r][nt*16 + l15] = f2bf(mv);
                macc[nt] += mv;
            }
        }
        __builtin_amdgcn_wave_barrier();

        // ---- stage 3: cw = silu(m @ Wc1 + bc1) @ Wc2; accumulate diff*cw ----
        // unroll 2 is safe here (p[r]/af2[kc] indices stay compile-time) and
        // halves the hoisted B-fragment transients.
        short8 af2[4];
        #pragma unroll
        for (int kc = 0; kc < 4; ++kc)
            af2[kc] = *(const short8*)&s_m[w][l15][kc*32 + q*8];
        float p[4] = {0.f, 0.f, 0.f, 0.f};
        #pragma unroll 2
        for (int nt = 0; nt < 8; ++nt) {
            float bias = s_c[4][nt*16 + l15];
            f32x4 c = {bias, bias, bias, bias};
            #pragma unroll
            for (int kc = 0; kc < 4; ++kc) {
                short8 bf = *(const short8*)&Wp3[(size_t)((kc*128 + nt*16 + l15)*4 + q)*8];
                c = __builtin_amdgcn_mfma_f32_16x16x32_bf16(af2[kc], bf, c, 0, 0, 0);
            }
            float wcv = s_c[5][nt*16 + l15];
            #pragma unroll
            for (int r = 0; r < 4; ++r)
                p[r] += silu_(c[r]) * wcv;
        }
        // reduce p over the 16 l15-lanes of this q-group -> cw per edge q*4+r
        #pragma unroll
        for (int m = 1; m < 16; m <<= 1) {
            #pragma unroll
            for (int r = 0; r < 4; ++r) p[r] += __shfl_xor(p[r], m, 64);
        }
        if (l15 < 3) {                              // lane d=l15 accumulates dim d
            #pragma unroll
            for (int r = 0; r < 4; ++r)
                xacc += s_es[w][q*4 + r][l15] * p[r];   // padding: diff=0
        }
        __builtin_amdgcn_wave_barrier();
    }

    // ---- cross-q, cross-wave combine; direct stores (no atomics, no pre-zero) ----
    #pragma unroll
    for (int nt = 0; nt < 8; ++nt) {
        macc[nt] += __shfl_xor(macc[nt], 16, 64);
        macc[nt] += __shfl_xor(macc[nt], 32, 64);
    }
    if (q == 0) {
        #pragma unroll
        for (int nt = 0; nt < 8; ++nt) s_mr[w][nt*16 + l15] = macc[nt];
    }
    xacc += __shfl_xor(xacc, 16, 64);
    xacc += __shfl_xor(xacc, 32, 64);
    if (q == 0 && l15 < 3) s_xr[w][l15] = xacc;
    __syncthreads();
    if (t < HID_) {
        aggm[(size_t)node*HID_ + t] = s_mr[0][t] + s_mr[1][t] + s_mr[2][t] + s_mr[3][t];
    } else if (t < HID_ + 3) {
        int d = t - HID_;
        aggx[node*4 + d] = s_xr[0][d] + s_xr[1][d] + s_xr[2][d] + s_xr[3][d];
    }
}

// ====== per-layer: node update (8 nodes/block) + next-layer W1 (folded) + out ======
__global__ __launch_bounds__(128) void k_update(
    float* __restrict__ feat_h, float* __restrict__ x,
    const float* __restrict__ aggm, const float* __restrict__ aggx,
    const float* __restrict__ Wn1, const float* __restrict__ bn1,
    const float* __restrict__ Wn2, const float* __restrict__ bn2, int l,
    const float* __restrict__ W1, const float* __restrict__ b1,
    const float* __restrict__ t_in,
    float* __restrict__ hiW1, float* __restrict__ hjW1, int do_w1,
    const float* __restrict__ x0h, const float* __restrict__ amask,
    float* __restrict__ out)
{
    __shared__ float s_in[8][NDIM_ + 1];
    __shared__ float s_u[8][HID_ + 1];
    int node0 = blockIdx.x * 8;            // bs*H + h
    int t = threadIdx.x;
    for (int idx = t; idx < 8*(NDIM_ + 1); idx += 128) {
        int g = idx / (NDIM_ + 1), k = idx % (NDIM_ + 1);
        float v = 0.f;
        if (k < FDIM_)      v = feat_h[(node0 + g)*FS_ + k];
        else if (k < NDIM_) v = aggm[(size_t)(node0 + g)*HID_ + (k - FDIM_)];
        s_in[g][k] = v;
    }
    __syncthreads();
    const float* Wn1l = Wn1 + l*NDIM_*HID_;
    float acc[8];
    float bv = bn1[l*HID_ + t];
    #pragma unroll
    for (int g = 0; g < 8; ++g) acc[g] = bv;
    for (int k = 0; k < NDIM_; ++k) {
        float wv = Wn1l[k*HID_ + t];
        #pragma unroll
        for (int g = 0; g < 8; ++g) acc[g] += s_in[g][k] * wv;
    }
    #pragma unroll
    for (int g = 0; g < 8; ++g) s_u[g][t] = silu_(acc[g]);
    __syncthreads();
    if (t < FDIM_) {
        const float* Wn2l = Wn2 + l*HID_*FDIM_;
        float acc2[8];
        float b2v = bn2[l*FDIM_ + t];
        #pragma unroll
        for (int g = 0; g < 8; ++g) acc2[g] = b2v;
        for (int k = 0; k < HID_; ++k) {
            float wv = Wn2l[k*FDIM_ + t];
            #pragma unroll
            for (int g = 0; g < 8; ++g) acc2[g] += s_u[g][k] * wv;
        }
        #pragma unroll
        for (int g = 0; g < 8; ++g) {
            float nf = s_in[g][t] + acc2[g];
            feat_h[(node0 + g)*FS_ + t] = nf;
            s_in[g][t] = nf;
        }
    } else if (t >= 96 && t < 120) {
        int idx = t - 96, g = idx / 3, d = idx % 3;
        int node = node0 + g;
        int bs = node / H_, h = node % H_;
        float xv = x[(bs*NN_ + h)*4 + d] + aggx[node*4 + d];
        x[(bs*NN_ + h)*4 + d] = xv;
        if (!do_w1) {
            int b = bs / S_;
            out[node*3 + d] = (xv - x0h[node*4 + d]) * amask[b*H_ + h];
        }
    }
    if (!do_w1) return;
    __syncthreads();
    // ---- next-layer W1 projections (fold b1 + t*w160 into hiW1) ----
    {
        const float* W1n = W1 + (l + 1)*EDIM_*HID_;
        float w160 = W1n[160*HID_ + t];
        float b1v  = b1[(l + 1)*HID_ + t];
        float hia[8], hja[8];
        #pragma unroll
        for (int g = 0; g < 8; ++g) { hia[g] = 0.f; hja[g] = 0.f; }
        for (int f = 0; f < FDIM_; ++f) {
            float wi = W1n[f*HID_ + t];
            float wj = W1n[(FDIM_ + f)*HID_ + t];
            #pragma unroll
            for (int g = 0; g < 8; ++g) {
                float v = s_in[g][f];
                hia[g] += v * wi;
                hja[g] += v * wj;
            }
        }
        #pragma unroll
        for (int g = 0; g < 8; ++g) {
            int node = node0 + g;
            int b = (node / H_) / S_;
            hiW1[(size_t)node*HID_ + t] = hia[g] + b1v + t_in[b]*w160;
            hjW1[(size_t)node*HID_ + t] = hja[g];
        }
    }
}

// ---------------- launch ----------------
extern "C" void kernel_launch(void* const* d_in, const int* in_sizes, int n_in,
                              void* d_out, int out_size, void* d_ws, size_t ws_size,
                              hipStream_t stream)
{
    const float* t_in  = (const float*)d_in[0];
    const float* x_h   = (const float*)d_in[1];
    const float* x_hv  = (const float*)d_in[2];
    const float* bond  = (const float*)d_in[3];
    const float* em_hv = (const float*)d_in[4];
    const float* em_hh = (const float*)d_in[5];
    const float* amask = (const float*)d_in[6];
    const float* W1    = (const float*)d_in[7];
    const float* b1    = (const float*)d_in[8];
    const float* W2    = (const float*)d_in[9];
    const float* b2    = (const float*)d_in[10];
    const float* Wc1   = (const float*)d_in[11];
    const float* bc1   = (const float*)d_in[12];
    const float* Wc2   = (const float*)d_in[13];
    const float* Wn1   = (const float*)d_in[14];
    const float* bn1   = (const float*)d_in[15];
    const float* Wn2   = (const float*)d_in[16];
    const float* bn2   = (const float*)d_in[17];
    const int* pep     = (const int*)d_in[18];
    const int* lab_hv  = (const int*)d_in[19];
    const int* lab_h   = (const int*)d_in[20];
    const int* pos_hv  = (const int*)d_in[21];
    const int* pos_h   = (const int*)d_in[22];
    const int* ehh     = (const int*)d_in[23];
    const int* bound   = (const int*)d_in[24];

    float* ws     = (float*)d_ws;
    float* feat_h = ws + OFF_FEATH;
    float* x      = ws + OFF_X;
    float* x0h    = ws + OFF_X0H;
    int*   hhcol  = (int*)(ws + OFF_HHCOL);
    float* hhem   = ws + OFF_HHEM;
    int*   hhoff  = (int*)(ws + OFF_HHOFF);
    float* hiW1   = ws + OFF_HIW1;
    float* hjW1   = ws + OFF_HJW1;
    unsigned short* Wp = (unsigned short*)(ws + OFF_WP);

    hipLaunchKernelGGL(k_setup, dim3(SETUP_BLKS_), dim3(256), 0, stream,
                       x_h, x_hv, bound, ehh, em_hh,
                       W1, b1, t_in, W2, Wc1,
                       lab_h, pos_h, lab_hv, pos_hv, pep,
                       feat_h, x, x0h, hhcol, hhem, hhoff,
                       hiW1, hjW1, Wp);

    for (int l = 0; l < L_; ++l) {
        float* aggx_l = ws + OFF_AGG0 + (size_t)l*AGGSTRIDE_;
        float* aggm_l = aggx_l + 6400;
        hipLaunchKernelGGL(k_edge_mlp, dim3(NROW_), dim3(256), 0, stream,
                           x, hiW1, hjW1, hhcol, hhem, hhoff, em_hv, bond,
                           W1, b2, bc1, Wc2, Wp, l, aggx_l, aggm_l);
        int do_w1 = (l == 0);
        hipLaunchKernelGGL(k_update, dim3(200), dim3(128), 0, stream,
                           feat_h, x, aggm_l, aggx_l, Wn1, bn1, Wn2, bn2, l,
                           W1, b1, t_in, hiW1, hjW1, do_w1,
                           x0h, amask, (float*)d_out);
    }
}

// Round 6
// 379.946 us; speedup vs baseline: 2.1754x; 1.6962x over previous
//
#include <hip/hip_runtime.h>
#include <math.h>

// Problem constants
#define B_     8
#define S_     4
#define H_     50
#define NH_    200
#define EHH_   400
#define L_     2
#define HID_   128
#define FDIM_  79          // 44 + 20 + 15
#define EDIM_  161         // 2*FDIM + 3
#define NN_    250         // H + NH
#define NROW_  1600        // BS*H
#define BS_    32          // B*S
#define FS_    80          // feat row stride
#define MSTR_  136         // s_m stride in bf16 (128 + 8)
#define NDIM_  207         // FDIM + HID
#define HVB_   1600        // hjW1 heavy-region base row

// Workspace layout (float offsets)
#define OFF_FEATH  0         // BS*H*80 = 128000
#define OFF_X      128000    // BS*NN*4 = 32000
#define OFF_X0H    160000    // 6400
#define OFF_HHCOL  166400    // 3200 (int)  sorted hh cols, 400 per b
#define OFF_HHEM   169600    // 3200        sorted hh edge masks
#define OFF_HHOFF  172800    // 512 (int)   CSR row offsets, 64 per b (0..50 used)
#define OFF_AGG0   173312    // aggx(6400) + aggm(204800) = 211200
#define AGGSTRIDE_ 211200
#define OFF_AGG1   384512
#define OFF_HIW1   595712    // fp32 1600*128 (b1 + t*w160 folded in)
#define OFF_HJW1   800512    // fp32 4800*128: [0,1600) h cur | [1600,3200) hv l0 | [3200,4800) hv l1
#define OFF_WP     1414912   // 65536 ushort (16B-aligned: 1414912*4 % 16 == 0)

typedef __attribute__((ext_vector_type(8))) short short8;
typedef __attribute__((ext_vector_type(4))) float f32x4;

__device__ __forceinline__ float silu_(float v) {
    return v * __builtin_amdgcn_rcpf(1.0f + __expf(-v));
}
__device__ __forceinline__ unsigned short f2bf(float f) {
    unsigned int u = __float_as_uint(f);
    unsigned int r = (u + 0x7fffu + ((u >> 16) & 1u)) >> 16;
    return (unsigned short)r;
}

// ================= fused setup =================
#define HV_BLKS_    1600   // heavy hjW1 both layers: 409600
#define PACK_BLKS_  256    // 65536
#define SORT_BLKS_  8      // counting-sort hh edges by row, per b; emits CSR
#define HROW_BLKS_  200    // 400*128
#define FEAT_BLKS_  125    // 400*80
#define XI_BLKS_    32     // 8000
#define SETUP_BLKS_ (HV_BLKS_ + PACK_BLKS_ + SORT_BLKS_ + HROW_BLKS_ + FEAT_BLKS_ + XI_BLKS_)

__global__ __launch_bounds__(256) void k_setup(
    const float* __restrict__ x_h, const float* __restrict__ x_hv,
    const int* __restrict__ bound,
    const int* __restrict__ ehh, const float* __restrict__ em_hh,
    const float* __restrict__ W1, const float* __restrict__ b1,
    const float* __restrict__ t_in,
    const float* __restrict__ W2, const float* __restrict__ Wc1,
    const int* __restrict__ lab_h, const int* __restrict__ pos_h,
    const int* __restrict__ lab_hv, const int* __restrict__ pos_hv,
    const int* __restrict__ pep,
    float* __restrict__ feat_h,
    float* __restrict__ x, float* __restrict__ x0h,
    int* __restrict__ hhcol, float* __restrict__ hhem, int* __restrict__ hhoff,
    float* __restrict__ hiW1, float* __restrict__ hjW1,
    unsigned short* __restrict__ Wp)
{
    int blk = blockIdx.x, t = threadIdx.x;
    if (blk < HV_BLKS_) {
        int g = blk*256 + t;                 // [0, 409600)
        int l = g / 204800;
        int r = g - l*204800;
        int node = r >> 7, col = r & 127;    // node = b*NH + nh
        int b = node / NH_;
        int label = lab_hv[node], pos = pos_hv[node];
        int aa = pep[b*15 + pos - 1];
        const float* W1l = W1 + l*EDIM_*HID_;
        float hj = W1l[(FDIM_ + label)*HID_ + col]
                 + W1l[(FDIM_ + 44 + aa)*HID_ + col]
                 + W1l[(FDIM_ + 64 + pos - 1)*HID_ + col];
        hjW1[(size_t)(HVB_ + l*1600 + node)*HID_ + col] = hj;
        return;
    }
    blk -= HV_BLKS_;
    if (blk < PACK_BLKS_) {
        int g = blk*256 + t;
        int idx = g & 16383;
        int lm  = g >> 14;
        int l = lm >> 1, mat = lm & 1;
        int j = idx & 7, q = (idx >> 3) & 3, n = (idx >> 5) & 127, kc = idx >> 12;
        int k = kc*32 + q*8 + j;
        const float* W = (mat == 0 ? W2 : Wc1) + l*HID_*HID_;
        Wp[g] = f2bf(W[k*HID_ + n]);
        return;
    }
    blk -= PACK_BLKS_;
    if (blk < SORT_BLKS_) {
        // counting-sort the 400 hh edges of batch b by row; emit CSR offsets
        int b = blk;
        __shared__ int scnt[64];
        __shared__ int srow[EHH_], scol[EHH_];
        __shared__ float sem[EHH_];
        if (t < 64) scnt[t] = 0;
        __syncthreads();
        for (int e = t; e < EHH_; e += 256) {
            int r = ehh[(b*EHH_ + e)*2 + 0];
            srow[e] = r;
            scol[e] = ehh[(b*EHH_ + e)*2 + 1];
            sem[e]  = em_hh[b*EHH_ + e];
            atomicAdd(&scnt[r], 1);
        }
        __syncthreads();
        if (t == 0) {
            int acc = 0;
            for (int i = 0; i < H_; ++i) { int v = scnt[i]; scnt[i] = acc; acc += v; }
        }
        __syncthreads();
        if (t < 51) hhoff[b*64 + t] = (t < H_) ? scnt[t] : EHH_;
        __syncthreads();
        for (int e = t; e < EHH_; e += 256) {
            int r = srow[e];
            int pos = atomicAdd(&scnt[r], 1);
            hhcol[b*EHH_ + pos] = scol[e];
            hhem [b*EHH_ + pos] = sem[e];
        }
        return;
    }
    blk -= SORT_BLKS_;
    if (blk < HROW_BLKS_) {
        // h-node layer-0 projections; fold b1 and t*w160 into hiW1
        int g = blk*256 + t;                 // [0, 51200)
        int node = g >> 7, col = g & 127;    // node = b*H + h
        int b = node / H_;
        int label = lab_h[node], pos = pos_h[node];
        int aa = pep[b*15 + pos - 1];
        const float* W1l = W1;               // layer 0
        float hi = W1l[label*HID_ + col]
                 + W1l[(44 + aa)*HID_ + col]
                 + W1l[(64 + pos - 1)*HID_ + col]
                 + b1[col]
                 + t_in[b] * W1l[160*HID_ + col];
        float hj = W1l[(FDIM_ + label)*HID_ + col]
                 + W1l[(FDIM_ + 44 + aa)*HID_ + col]
                 + W1l[(FDIM_ + 64 + pos - 1)*HID_ + col];
        int h = node % H_;
        #pragma unroll
        for (int s = 0; s < S_; ++s) {
            int row = (b*S_ + s)*H_ + h;
            hiW1[(size_t)row*HID_ + col] = hi;
            hjW1[(size_t)row*HID_ + col] = hj;
        }
        return;
    }
    blk -= HROW_BLKS_;
    if (blk < FEAT_BLKS_) {
        int g = blk*256 + t;                 // [0, 32000)
        int node = g / FS_, f = g % FS_;     // node = b*H + h
        int b = node / H_, h = node % H_;
        int label = lab_h[node], pos = pos_h[node];
        int aa = pep[b*15 + pos - 1];
        float v = 0.f;
        if (f < 44)      v = (f == label)          ? 1.0f : 0.0f;
        else if (f < 64) v = ((f - 44) == aa)      ? 1.0f : 0.0f;
        else if (f < 79) v = ((f - 64) == pos - 1) ? 1.0f : 0.0f;
        #pragma unroll
        for (int s = 0; s < S_; ++s)
            feat_h[((b*S_ + s)*H_ + h)*FS_ + f] = v;
        return;
    }
    blk -= FEAT_BLKS_;
    {
        int g = blk*256 + t;
        if (g >= BS_*NN_) return;
        int bs = g / NN_, n = g % NN_;
        int b = bs / S_;
        if (n < H_) {
            int ba = bound[b*H_ + n];
            for (int d = 0; d < 3; ++d) {
                float v = x_h[(bs*H_ + n)*3 + d] + x_hv[(b*NH_ + ba)*3 + d];
                x[g*4 + d] = v;
                x0h[(bs*H_ + n)*4 + d] = v;
            }
        } else {
            int nh = n - H_;
            for (int d = 0; d < 3; ++d) x[g*4 + d] = x_hv[(b*NH_ + nh)*3 + d];
        }
    }
}

// ============ per-layer: 2 rows per block, 512 threads; weights staged in LDS ============
// Waves 0-3 own row node0, waves 4-7 own row node0+1. Each wave independently
// processes 16-edge tiles (ti = wr, wr+4, ...) of its row's edge list. Per-tile
// LDS (s_m/s_es/s_jj) is wave-private (wave_barrier ordering). aggm/aggx
// accumulate in registers; single cross-wave combine + direct store.
//
// R5 post-mortem: occupancy never moves (~3.4 waves/CU effective in R2 AND R5);
// the regime is latency-bound and per-wave ILP is what pays (R2@248VGPR=166us vs
// R5@132VGPR=240us, same occupancy). The dominant exposed latency was the per-MFMA
// global load of Wp B-fragments (~1.3 GB L2 traffic/dispatch). Fix: stage
// Wp2+Wp3 (64 KB) in LDS once per block -> conflict-free ds_read_b128.
// __launch_bounds__(512) hardware-forces VGPR<=256 (2 waves/EU to host one
// workgroup) -> R2-style ILP budget with no spill-chasing possible (LDS-derived
// occupancy target is also 2 waves/EU; cf. R3/R4 failure).
__global__ __launch_bounds__(512) void k_edge_mlp(
    const float* __restrict__ x, const float* __restrict__ hiW1,
    const float* __restrict__ hjW1,
    const int* __restrict__ hhcol, const float* __restrict__ hhem,
    const int* __restrict__ hhoff,
    const float* __restrict__ em_hv, const float* __restrict__ bond_in,
    const float* __restrict__ W1,
    const float* __restrict__ b2, const float* __restrict__ bc1,
    const float* __restrict__ Wc2,
    const unsigned short* __restrict__ Wp, int l,
    float* __restrict__ aggx, float* __restrict__ aggm)
{
    __shared__ unsigned short s_wp[2*16384];       // 65536 B: [0]=Wp2, [1]=Wp3
    __shared__ unsigned short s_m[8][16][MSTR_];   // 34816 B, wave-private 16-row chunks
    __shared__ float s_es[8][16][6];               // 3072 B: diff0..2, dist, bond, emk
    __shared__ int   s_jj[8][16];                  // 512 B
    __shared__ float s_hi[2][HID_];                // 1024 B: per-row hiW1
    __shared__ float s_cc[5][HID_];                // 2560 B: W1r158, W1r159, b2, bc1, Wc2
    __shared__ float s_mr[2][4][HID_];             // 4096 B
    __shared__ float s_xr[2][4][4];                // 128 B
    // total ~111.7 KB -> 1 block/CU, 8 waves (2/SIMD)

    const int t = threadIdx.x, lane = t & 63, w = t >> 6;
    const int l15 = lane & 15, q = lane >> 4;
    const int r  = w >> 2;                         // row-in-block (0/1)
    const int wr = w & 3;                          // wave-in-row
    const int node0 = blockIdx.x*2;
    const int node  = node0 + r;                   // bs*H + h
    const int bs = node / H_, h = node - bs*H_;
    const int b  = bs / S_;

    // ---- stage weights Wp2|Wp3 (contiguous 64 KB) into LDS ----
    {
        const float4* src = (const float4*)(Wp + (size_t)l*32768);
        float4* dst = (float4*)s_wp;
        #pragma unroll
        for (int i = 0; i < 8; ++i) dst[t + i*512] = src[t + i*512];
    }
    const float* W1l = W1 + l*EDIM_*HID_;
    if (t < 128) {
        s_hi[0][t] = hiW1[(size_t)node0*HID_ + t];
    } else if (t < 256) {
        int c = t - 128;
        s_hi[1][c] = hiW1[(size_t)(node0 + 1)*HID_ + c];
    } else if (t < 384) {
        int c = t - 256;
        s_cc[0][c] = W1l[158*HID_ + c];
        s_cc[3][c] = bc1[l*HID_ + c];
    } else {
        int c = t - 384;
        s_cc[1][c] = W1l[159*HID_ + c];
        s_cc[2][c] = b2 [l*HID_ + c];
        s_cc[4][c] = Wc2[l*HID_ + c];
    }

    const int hh0 = hhoff[b*64 + h];
    const int cnt = hhoff[b*64 + h + 1] - hh0;
    const int E   = cnt + NH_;                     // total real edges for this row
    const int NT  = (E + 15) >> 4;                 // 16-edge tiles

    const float xi0 = x[(bs*NN_ + h)*4 + 0];
    const float xi1 = x[(bs*NN_ + h)*4 + 1];
    const float xi2 = x[(bs*NN_ + h)*4 + 2];

    float macc[8] = {0.f,0.f,0.f,0.f,0.f,0.f,0.f,0.f};
    float xacc = 0.f;
    __syncthreads();                               // s_wp/s_hi/s_cc ready

    for (int ti = wr; ti < NT; ti += 4) {
        // ---- per-edge scalars for this wave's 16 edges ----
        if (lane < 16) {
            int e = ti*16 + lane;
            float d0=0.f,d1=0.f,d2=0.f,dist=0.f,bnd=0.f,em=0.f;
            int jj = bs*H_;                        // padding: valid row, em=0, diff=0
            if (e < E) {
                int col;
                if (e < cnt) {                     // sorted hh edge
                    col = hhcol[b*EHH_ + hh0 + e];
                    em  = hhem [b*EHH_ + hh0 + e];
                    jj  = bs*H_ + col;
                } else {                           // grid edge (row h -> heavy cc)
                    int cc = e - cnt;
                    col = H_ + cc;
                    em  = em_hv [(b*H_ + h)*NH_ + cc];
                    bnd = bond_in[(b*H_ + h)*NH_ + cc];
                    jj  = HVB_ + l*1600 + b*NH_ + cc;
                }
                d0 = xi0 - x[(bs*NN_ + col)*4 + 0];
                d1 = xi1 - x[(bs*NN_ + col)*4 + 1];
                d2 = xi2 - x[(bs*NN_ + col)*4 + 2];
                dist = sqrtf(d0*d0 + d1*d1 + d2*d2);
            }
            s_es[w][lane][0] = d0; s_es[w][lane][1] = d1; s_es[w][lane][2] = d2;
            s_es[w][lane][3] = dist; s_es[w][lane][4] = bnd; s_es[w][lane][5] = em;
            s_jj[w][lane] = jj;
        }
        __builtin_amdgcn_wave_barrier();

        // ---- stage 1: m1 = silu(hi + hj + dist*w158 + bond*w159) ----
        const float dist = s_es[w][l15][3];
        const float bnd  = s_es[w][l15][4];
        const int   jj   = s_jj[w][l15];
        const float* pj  = hjW1 + (size_t)jj*HID_ + q*8;
        short8 afrag[4];
        #pragma unroll
        for (int kc = 0; kc < 4; ++kc) {
            int k0 = kc*32 + q*8;
            float4 c0 = *(const float4*)(pj + kc*32);
            float4 c1 = *(const float4*)(pj + kc*32 + 4);
            float4 h0 = *(const float4*)&s_hi[r][k0];
            float4 h1 = *(const float4*)&s_hi[r][k0 + 4];
            float4 wa0= *(const float4*)&s_cc[0][k0];
            float4 wa1= *(const float4*)&s_cc[0][k0 + 4];
            float4 wb0= *(const float4*)&s_cc[1][k0];
            float4 wb1= *(const float4*)&s_cc[1][k0 + 4];
            short8 fr;
            fr[0] = (short)f2bf(silu_(h0.x + c0.x + dist*wa0.x + bnd*wb0.x));
            fr[1] = (short)f2bf(silu_(h0.y + c0.y + dist*wa0.y + bnd*wb0.y));
            fr[2] = (short)f2bf(silu_(h0.z + c0.z + dist*wa0.z + bnd*wb0.z));
            fr[3] = (short)f2bf(silu_(h0.w + c0.w + dist*wa0.w + bnd*wb0.w));
            fr[4] = (short)f2bf(silu_(h1.x + c1.x + dist*wa1.x + bnd*wb1.x));
            fr[5] = (short)f2bf(silu_(h1.y + c1.y + dist*wa1.y + bnd*wb1.y));
            fr[6] = (short)f2bf(silu_(h1.z + c1.z + dist*wa1.z + bnd*wb1.z));
            fr[7] = (short)f2bf(silu_(h1.w + c1.w + dist*wa1.w + bnd*wb1.w));
            afrag[kc] = fr;
        }

        // ---- stage 2: m = silu(m1 @ W2 + b2) * emask; accumulate column sums ----
        // nt loop stays FULLY unrolled: macc[nt] needs compile-time index (rule #20)
        float em4[4];
        #pragma unroll
        for (int rr = 0; rr < 4; ++rr) em4[rr] = s_es[w][q*4 + rr][5];
        #pragma unroll
        for (int nt = 0; nt < 8; ++nt) {
            float bias = s_cc[2][nt*16 + l15];
            f32x4 c = {bias, bias, bias, bias};
            #pragma unroll
            for (int kc = 0; kc < 4; ++kc) {
                short8 bf = *(const short8*)&s_wp[((kc*128 + nt*16 + l15)*4 + q)*8];
                c = __builtin_amdgcn_mfma_f32_16x16x32_bf16(afrag[kc], bf, c, 0, 0, 0);
            }
            #pragma unroll
            for (int rr = 0; rr < 4; ++rr) {
                float mv = silu_(c[rr]) * em4[rr]; // padding edges have em=0 -> mv=0
                s_m[w][q*4 + rr][nt*16 + l15] = f2bf(mv);
                macc[nt] += mv;
            }
        }
        __builtin_amdgcn_wave_barrier();

        // ---- stage 3: cw = silu(m @ Wc1 + bc1) @ Wc2; accumulate diff*cw ----
        short8 af2[4];
        #pragma unroll
        for (int kc = 0; kc < 4; ++kc)
            af2[kc] = *(const short8*)&s_m[w][l15][kc*32 + q*8];
        float p[4] = {0.f, 0.f, 0.f, 0.f};
        #pragma unroll
        for (int nt = 0; nt < 8; ++nt) {
            float bias = s_cc[3][nt*16 + l15];
            f32x4 c = {bias, bias, bias, bias};
            #pragma unroll
            for (int kc = 0; kc < 4; ++kc) {
                short8 bf = *(const short8*)&s_wp[16384 + ((kc*128 + nt*16 + l15)*4 + q)*8];
                c = __builtin_amdgcn_mfma_f32_16x16x32_bf16(af2[kc], bf, c, 0, 0, 0);
            }
            float wcv = s_cc[4][nt*16 + l15];
            #pragma unroll
            for (int rr = 0; rr < 4; ++rr)
                p[rr] += silu_(c[rr]) * wcv;
        }
        // reduce p over the 16 l15-lanes of this q-group -> cw per edge q*4+rr
        #pragma unroll
        for (int m = 1; m < 16; m <<= 1) {
            #pragma unroll
            for (int rr = 0; rr < 4; ++rr) p[rr] += __shfl_xor(p[rr], m, 64);
        }
        if (l15 < 3) {                              // lane d=l15 accumulates dim d
            #pragma unroll
            for (int rr = 0; rr < 4; ++rr)
                xacc += s_es[w][q*4 + rr][l15] * p[rr];  // padding: diff=0
        }
        __builtin_amdgcn_wave_barrier();
    }

    // ---- cross-q, cross-wave combine; direct stores (no atomics, no pre-zero) ----
    #pragma unroll
    for (int nt = 0; nt < 8; ++nt) {
        macc[nt] += __shfl_xor(macc[nt], 16, 64);
        macc[nt] += __shfl_xor(macc[nt], 32, 64);
    }
    if (q == 0) {
        #pragma unroll
        for (int nt = 0; nt < 8; ++nt) s_mr[r][wr][nt*16 + l15] = macc[nt];
    }
    xacc += __shfl_xor(xacc, 16, 64);
    xacc += __shfl_xor(xacc, 32, 64);
    if (q == 0 && l15 < 3) s_xr[r][wr][l15] = xacc;
    __syncthreads();
    if (t < 256) {
        int rr = t >> 7, col = t & 127;
        aggm[(size_t)(node0 + rr)*HID_ + col] =
            s_mr[rr][0][col] + s_mr[rr][1][col] + s_mr[rr][2][col] + s_mr[rr][3][col];
    } else if (t < 262) {
        int ix = t - 256, rr = ix / 3, d = ix - rr*3;
        aggx[(node0 + rr)*4 + d] =
            s_xr[rr][0][d] + s_xr[rr][1][d] + s_xr[rr][2][d] + s_xr[rr][3][d];
    }
}

// ====== per-layer: node update (8 nodes/block) + next-layer W1 (folded) + out ======
__global__ __launch_bounds__(128) void k_update(
    float* __restrict__ feat_h, float* __restrict__ x,
    const float* __restrict__ aggm, const float* __restrict__ aggx,
    const float* __restrict__ Wn1, const float* __restrict__ bn1,
    const float* __restrict__ Wn2, const float* __restrict__ bn2, int l,
    const float* __restrict__ W1, const float* __restrict__ b1,
    const float* __restrict__ t_in,
    float* __restrict__ hiW1, float* __restrict__ hjW1, int do_w1,
    const float* __restrict__ x0h, const float* __restrict__ amask,
    float* __restrict__ out)
{
    __shared__ float s_in[8][NDIM_ + 1];
    __shared__ float s_u[8][HID_ + 1];
    int node0 = blockIdx.x * 8;            // bs*H + h
    int t = threadIdx.x;
    for (int idx = t; idx < 8*(NDIM_ + 1); idx += 128) {
        int g = idx / (NDIM_ + 1), k = idx % (NDIM_ + 1);
        float v = 0.f;
        if (k < FDIM_)      v = feat_h[(node0 + g)*FS_ + k];
        else if (k < NDIM_) v = aggm[(size_t)(node0 + g)*HID_ + (k - FDIM_)];
        s_in[g][k] = v;
    }
    __syncthreads();
    const float* Wn1l = Wn1 + l*NDIM_*HID_;
    float acc[8];
    float bv = bn1[l*HID_ + t];
    #pragma unroll
    for (int g = 0; g < 8; ++g) acc[g] = bv;
    for (int k = 0; k < NDIM_; ++k) {
        float wv = Wn1l[k*HID_ + t];
        #pragma unroll
        for (int g = 0; g < 8; ++g) acc[g] += s_in[g][k] * wv;
    }
    #pragma unroll
    for (int g = 0; g < 8; ++g) s_u[g][t] = silu_(acc[g]);
    __syncthreads();
    if (t < FDIM_) {
        const float* Wn2l = Wn2 + l*HID_*FDIM_;
        float acc2[8];
        float b2v = bn2[l*FDIM_ + t];
        #pragma unroll
        for (int g = 0; g < 8; ++g) acc2[g] = b2v;
        for (int k = 0; k < HID_; ++k) {
            float wv = Wn2l[k*FDIM_ + t];
            #pragma unroll
            for (int g = 0; g < 8; ++g) acc2[g] += s_u[g][k] * wv;
        }
        #pragma unroll
        for (int g = 0; g < 8; ++g) {
            float nf = s_in[g][t] + acc2[g];
            feat_h[(node0 + g)*FS_ + t] = nf;
            s_in[g][t] = nf;
        }
    } else if (t >= 96 && t < 120) {
        int idx = t - 96, g = idx / 3, d = idx % 3;
        int node = node0 + g;
        int bs = node / H_, h = node % H_;
        float xv = x[(bs*NN_ + h)*4 + d] + aggx[node*4 + d];
        x[(bs*NN_ + h)*4 + d] = xv;
        if (!do_w1) {
            int b = bs / S_;
            out[node*3 + d] = (xv - x0h[node*4 + d]) * amask[b*H_ + h];
        }
    }
    if (!do_w1) return;
    __syncthreads();
    // ---- next-layer W1 projections (fold b1 + t*w160 into hiW1) ----
    {
        const float* W1n = W1 + (l + 1)*EDIM_*HID_;
        float w160 = W1n[160*HID_ + t];
        float b1v  = b1[(l + 1)*HID_ + t];
        float hia[8], hja[8];
        #pragma unroll
        for (int g = 0; g < 8; ++g) { hia[g] = 0.f; hja[g] = 0.f; }
        for (int f = 0; f < FDIM_; ++f) {
            float wi = W1n[f*HID_ + t];
            float wj = W1n[(FDIM_ + f)*HID_ + t];
            #pragma unroll
            for (int g = 0; g < 8; ++g) {
                float v = s_in[g][f];
                hia[g] += v * wi;
                hja[g] += v * wj;
            }
        }
        #pragma unroll
        for (int g = 0; g < 8; ++g) {
            int node = node0 + g;
            int b = (node / H_) / S_;
            hiW1[(size_t)node*HID_ + t] = hia[g] + b1v + t_in[b]*w160;
            hjW1[(size_t)node*HID_ + t] = hja[g];
        }
    }
}

// ---------------- launch ----------------
extern "C" void kernel_launch(void* const* d_in, const int* in_sizes, int n_in,
                              void* d_out, int out_size, void* d_ws, size_t ws_size,
                              hipStream_t stream)
{
    const float* t_in  = (const float*)d_in[0];
    const float* x_h   = (const float*)d_in[1];
    const float* x_hv  = (const float*)d_in[2];
    const float* bond  = (const float*)d_in[3];
    const float* em_hv = (const float*)d_in[4];
    const float* em_hh = (const float*)d_in[5];
    const float* amask = (const float*)d_in[6];
    const float* W1    = (const float*)d_in[7];
    const float* b1    = (const float*)d_in[8];
    const float* W2    = (const float*)d_in[9];
    const float* b2    = (const float*)d_in[10];
    const float* Wc1   = (const float*)d_in[11];
    const float* bc1   = (const float*)d_in[12];
    const float* Wc2   = (const float*)d_in[13];
    const float* Wn1   = (const float*)d_in[14];
    const float* bn1   = (const float*)d_in[15];
    const float* Wn2   = (const float*)d_in[16];
    const float* bn2   = (const float*)d_in[17];
    const int* pep     = (const int*)d_in[18];
    const int* lab_hv  = (const int*)d_in[19];
    const int* lab_h   = (const int*)d_in[20];
    const int* pos_hv  = (const int*)d_in[21];
    const int* pos_h   = (const int*)d_in[22];
    const int* ehh     = (const int*)d_in[23];
    const int* bound   = (const int*)d_in[24];

    float* ws     = (float*)d_ws;
    float* feat_h = ws + OFF_FEATH;
    float* x      = ws + OFF_X;
    float* x0h    = ws + OFF_X0H;
    int*   hhcol  = (int*)(ws + OFF_HHCOL);
    float* hhem   = ws + OFF_HHEM;
    int*   hhoff  = (int*)(ws + OFF_HHOFF);
    float* hiW1   = ws + OFF_HIW1;
    float* hjW1   = ws + OFF_HJW1;
    unsigned short* Wp = (unsigned short*)(ws + OFF_WP);

    hipLaunchKernelGGL(k_setup, dim3(SETUP_BLKS_), dim3(256), 0, stream,
                       x_h, x_hv, bound, ehh, em_hh,
                       W1, b1, t_in, W2, Wc1,
                       lab_h, pos_h, lab_hv, pos_hv, pep,
                       feat_h, x, x0h, hhcol, hhem, hhoff,
                       hiW1, hjW1, Wp);

    for (int l = 0; l < L_; ++l) {
        float* aggx_l = ws + OFF_AGG0 + (size_t)l*AGGSTRIDE_;
        float* aggm_l = aggx_l + 6400;
        hipLaunchKernelGGL(k_edge_mlp, dim3(NROW_/2), dim3(512), 0, stream,
                           x, hiW1, hjW1, hhcol, hhem, hhoff, em_hv, bond,
                           W1, b2, bc1, Wc2, Wp, l, aggx_l, aggm_l);
        int do_w1 = (l == 0);
        hipLaunchKernelGGL(k_update, dim3(200), dim3(128), 0, stream,
                           feat_h, x, aggm_l, aggx_l, Wn1, bn1, Wn2, bn2, l,
                           W1, b1, t_in, hiW1, hjW1, do_w1,
                           x0h, amask, (float*)d_out);
    }
}